// Round 4
// baseline (560.349 us; speedup 1.0000x reference)
//
#include <hip/hip_runtime.h>
#include <hip/hip_bf16.h>

// Problem constants
#define B_SZ   4096
#define OBS_N  128
#define HID    512
#define CHUNK  65536       // q-MLP rows per chunk (B*S/2): 16 s-values x 4096 b

// Row ordering for the q pipeline is S-MAJOR: global row r = s*4096 + b.
// Chunk c covers s in [c*16, c*16+16). Layer-3 diagonal rows sharing s are
// contiguous (4096-row groups).
// Dispatch plan (10 total): prep | P(+v0) | 2 x { h0 | G1(+v1) | G2(+v2) | ADV(+value) }

typedef __bf16 bf16x8_t __attribute__((ext_vector_type(8)));
typedef float  f32x4_t  __attribute__((ext_vector_type(4)));

__device__ inline float fast_tanh(float x) {
    float xc = fminf(fmaxf(x, -15.f), 15.f);
    float e  = __expf(2.f * xc);
    return (e - 1.f) * __builtin_amdgcn_rcpf(e + 1.f);
}

__device__ inline void gld_lds16(const void* g, void* l) {
    __builtin_amdgcn_global_load_lds(
        (const __attribute__((address_space(1))) void*)g,
        (__attribute__((address_space(3))) void*)l, 16, 0, 0);
}

// ---------------- combined prep (obs cast, 7 weight transposes, actions, nbias) ----------------
// block ranges: [0,2048) obs | [2048,2304) w0t | [2304,2560) vw0t | [2560,3584) w1t
// [3584,4608) w2t | [4608,5632) w3t | [5632,6656) vw1t | [6656,7680) vw2t
// [7680,11776) actions | [11776,12288) nbias zero
__global__ __launch_bounds__(256) void prep_kernel(
    const float* __restrict__ obs, const int* __restrict__ category,
    const float* __restrict__ qw0, const float* __restrict__ qw1,
    const float* __restrict__ qw2, const float* __restrict__ qw3,
    const float* __restrict__ vw0, const float* __restrict__ vw1,
    const float* __restrict__ vw2,
    __hip_bfloat16* __restrict__ obs_bf,
    __hip_bfloat16* __restrict__ w0t, __hip_bfloat16* __restrict__ w1t,
    __hip_bfloat16* __restrict__ w2t, __hip_bfloat16* __restrict__ w3t,
    __hip_bfloat16* __restrict__ vw0t, __hip_bfloat16* __restrict__ vw1t,
    __hip_bfloat16* __restrict__ vw2t,
    float* __restrict__ acts, float* __restrict__ nbias)
{
    const int bid = blockIdx.x, tid = threadIdx.x;
    if (bid < 2048) {
        int i = bid * 256 + tid;
        obs_bf[i] = __float2bfloat16(obs[i]);
    } else if (bid < 2560) {   // (512,128) transposes
        const float* src = (bid < 2304) ? qw0 : vw0;
        __hip_bfloat16* dst = (bid < 2304) ? w0t : vw0t;
        int idx = ((bid - 2048) & 255) * 256 + tid;
        int n = idx >> 7, k = idx & 127;
        dst[idx] = __float2bfloat16(src[k * 512 + n]);
    } else if (bid < 7680) {   // (512,512) transposes
        int job = (bid - 2560) >> 10;            // 0..4
        const float* srcs[5] = {qw1, qw2, qw3, vw1, vw2};
        __hip_bfloat16* dsts[5] = {w1t, w2t, w3t, vw1t, vw2t};
        int idx = ((bid - 2560) & 1023) * 256 + tid;
        int n = idx >> 9, k = idx & 511;
        dsts[job][idx] = __float2bfloat16(srcs[job][k * 512 + n]);
    } else if (bid < 11776) {  // actions table, s-major: acts[(s*4096+b)*8+d]
        int t = (bid - 7680) * 256 + tid;
        int d = t & 7;
        int r = t >> 3;
        int b = r & 4095, s = r >> 12;
        int U = (s >> 3) + ((d < (s & 7)) ? 1 : 0);
        float a = 0.f;
        if (U > 0) {
            float w = 0.125f, cum = 0.f;
            for (int j = 0; j < U; ++j) {
                cum += (float)category[b * 32 + j * 8 + d] * w;
                if (j == U - 1) a = -1.f + cum + 0.5f * w;
                w *= 0.0625f;
            }
        }
        acts[t] = a;
    } else {                   // nbias = 0
        int i = (bid - 11776) * 256 + tid;
        nbias[i] = 0.f;
    }
}

// ---------------- dual-job GEMM (m97-style body) ----------------
// Job0 occupies x-blocks [0, nx0); job1 the rest. C(M,512) = A(M,K) @ Bt(512,K)^T.
// epi=0: fp32 raw store; epi=1: bf16(tanh(acc+bias)).
__global__ __launch_bounds__(256) void gemm_dual(
    const __hip_bfloat16* __restrict__ A0, const __hip_bfloat16* __restrict__ B0,
    const float* __restrict__ bias0, void* __restrict__ C0, int K0, int epi0, int nx0,
    const __hip_bfloat16* __restrict__ A1, const __hip_bfloat16* __restrict__ B1,
    const float* __restrict__ bias1, void* __restrict__ C1, int K1, int epi1)
{
    __shared__ __hip_bfloat16 As[128 * 32];
    __shared__ __hip_bfloat16 Bs[128 * 32];

    const __hip_bfloat16 *A, *Bt;
    const float* bias;
    void* Cout;
    int K, epi;
    long mblk;
    if ((int)blockIdx.x < nx0) {
        A = A0; Bt = B0; bias = bias0; Cout = C0; K = K0; epi = epi0; mblk = blockIdx.x;
    } else {
        A = A1; Bt = B1; bias = bias1; Cout = C1; K = K1; epi = epi1; mblk = blockIdx.x - nx0;
    }

    const int tid  = threadIdx.x;
    const int wave = tid >> 6, lane = tid & 63;
    const int quad = lane >> 4, t = lane & 15;
    const int wr = wave >> 1, wc = wave & 1;
    const long m0 = mblk * 128;
    const int  n0 = blockIdx.y * 128;

    f32x4_t acc[4][4] = {};

    const int lrow  = lane >> 2;       // 0..15
    const int lkoff = (lane & 3) * 8;  // element offset within 32-wide K chunk

    const __hip_bfloat16* Ag0 = A  + (m0 + wave * 32 +      lrow) * (long)K + lkoff;
    const __hip_bfloat16* Ag1 = A  + (m0 + wave * 32 + 16 + lrow) * (long)K + lkoff;
    const __hip_bfloat16* Bg0 = Bt + (long)(n0 + wave * 32 +      lrow) * K + lkoff;
    const __hip_bfloat16* Bg1 = Bt + (long)(n0 + wave * 32 + 16 + lrow) * K + lkoff;
    __hip_bfloat16* AsB0 = &As[(wave * 32) * 32];
    __hip_bfloat16* AsB1 = &As[(wave * 32 + 16) * 32];
    __hip_bfloat16* BsB0 = &Bs[(wave * 32) * 32];
    __hip_bfloat16* BsB1 = &Bs[(wave * 32 + 16) * 32];

    for (int k0 = 0; k0 < K; k0 += 32) {
        gld_lds16(Ag0 + k0, AsB0);
        gld_lds16(Ag1 + k0, AsB1);
        gld_lds16(Bg0 + k0, BsB0);
        gld_lds16(Bg1 + k0, BsB1);
        __syncthreads();
        bf16x8_t af[4], bfr[4];
        #pragma unroll
        for (int i = 0; i < 4; ++i)
            af[i] = *(const bf16x8_t*)&As[(wr * 64 + i * 16 + t) * 32 + quad * 8];
        #pragma unroll
        for (int j = 0; j < 4; ++j)
            bfr[j] = *(const bf16x8_t*)&Bs[(wc * 64 + j * 16 + t) * 32 + quad * 8];
        #pragma unroll
        for (int i = 0; i < 4; ++i)
            #pragma unroll
            for (int j = 0; j < 4; ++j)
                acc[i][j] = __builtin_amdgcn_mfma_f32_16x16x32_bf16(af[i], bfr[j], acc[i][j], 0, 0, 0);
        __syncthreads();
    }

    #pragma unroll
    for (int i = 0; i < 4; ++i) {
        const long rbase = m0 + wr * 64 + i * 16 + quad * 4;
        #pragma unroll
        for (int j = 0; j < 4; ++j) {
            const int col = n0 + wc * 64 + j * 16 + t;
            #pragma unroll
            for (int r = 0; r < 4; ++r) {
                float v = acc[i][j][r];
                if (epi) {
                    v = fast_tanh(v + bias[col]);
                    ((__hip_bfloat16*)Cout)[(rbase + r) * 512 + col] = __float2bfloat16(v);
                } else {
                    ((float*)Cout)[(rbase + r) * 512 + col] = v;
                }
            }
        }
    }
}

// ---------------- q layer 0: h0 = tanh(p[b] + acts(r)@W0b + b0) ----------------
// One WAVE per row; lane owns cols [lane*8, lane*8+8). 16 rows/wave, 64 rows/block.
__global__ __launch_bounds__(256) void h0_kernel(
    const float* __restrict__ p,         // (4096,512) fp32 = obs @ W0[:128]
    const float* __restrict__ acts,      // (131072,8) fp32 s-major
    const float* __restrict__ qw0,       // (136,512) fp32 (rows 128..135 = action part)
    const float* __restrict__ qb0,       // (512)
    __hip_bfloat16* __restrict__ h0,     // (CHUNK,512)
    int r0)
{
    const int wave = threadIdx.x >> 6, lane = threadIdx.x & 63;
    const int col0 = lane * 8;

    float w[8][8], bb[8];
    #pragma unroll
    for (int d = 0; d < 8; ++d) {
        float4 u0 = *(const float4*)&qw0[(128 + d) * 512 + col0];
        float4 u1 = *(const float4*)&qw0[(128 + d) * 512 + col0 + 4];
        w[d][0] = u0.x; w[d][1] = u0.y; w[d][2] = u0.z; w[d][3] = u0.w;
        w[d][4] = u1.x; w[d][5] = u1.y; w[d][6] = u1.z; w[d][7] = u1.w;
    }
    {
        float4 b0 = *(const float4*)&qb0[col0];
        float4 b1 = *(const float4*)&qb0[col0 + 4];
        bb[0] = b0.x; bb[1] = b0.y; bb[2] = b0.z; bb[3] = b0.w;
        bb[4] = b1.x; bb[5] = b1.y; bb[6] = b1.z; bb[7] = b1.w;
    }

    #pragma unroll 2
    for (int rr = 0; rr < 16; ++rr) {
        const int lr = blockIdx.x * 64 + wave * 16 + rr;
        const int b  = lr & 4095;
        const float4* pp = (const float4*)&p[(size_t)b * 512 + col0];
        float4 p0 = pp[0], p1 = pp[1];
        const float4* ap = (const float4*)&acts[(size_t)(r0 + lr) * 8];
        float4 a0 = ap[0], a1 = ap[1];
        float a[8] = {a0.x, a0.y, a0.z, a0.w, a1.x, a1.y, a1.z, a1.w};
        float v[8] = {p0.x + bb[0], p0.y + bb[1], p0.z + bb[2], p0.w + bb[3],
                      p1.x + bb[4], p1.y + bb[5], p1.z + bb[6], p1.w + bb[7]};
        #pragma unroll
        for (int d = 0; d < 8; ++d)
            #pragma unroll
            for (int cc = 0; cc < 8; ++cc)
                v[cc] = fmaf(a[d], w[d][cc], v[cc]);
        union { bf16x8_t vec; __hip_bfloat16 e[8]; } o;
        #pragma unroll
        for (int cc = 0; cc < 8; ++cc)
            o.e[cc] = __float2bfloat16(fast_tanh(v[cc]));
        *(bf16x8_t*)&h0[(size_t)lr * 512 + col0] = o.vec;
    }
}

// ---------------- q layer 3 diag (MFMA) + optional value-head blocks ----------------
__device__ inline float blo(unsigned u) { return __uint_as_float(u << 16); }
__device__ inline float bhi(unsigned u) { return __uint_as_float(u & 0xffff0000u); }

__global__ __launch_bounds__(256) void adv_kernel(
    const __hip_bfloat16* __restrict__ h2,   // (CHUNK,512) s-major
    const __hip_bfloat16* __restrict__ w3t,  // (512,512): [out][k]
    const float* __restrict__ qb3,
    float* __restrict__ advout,              // (4096,512) at d_out+4096
    int c,                                   // chunk index
    const __hip_bfloat16* __restrict__ hv2,  // (4096,512) v hidden
    const float* __restrict__ vw3, const float* __restrict__ vb3,
    float* __restrict__ vout)
{
    if ((int)blockIdx.x >= 512) {
        // value head: 16 blocks cover 4096 rows
        int b = ((int)blockIdx.x - 512) * 256 + threadIdx.x;
        const uint4* h = (const uint4*)(hv2 + (size_t)b * 512);
        float acc = 0.f;
        for (int i = 0; i < 64; ++i) {
            uint4 hu = h[i];
            const float* w = vw3 + i * 8;
            acc = fmaf(blo(hu.x), w[0], acc); acc = fmaf(bhi(hu.x), w[1], acc);
            acc = fmaf(blo(hu.y), w[2], acc); acc = fmaf(bhi(hu.y), w[3], acc);
            acc = fmaf(blo(hu.z), w[4], acc); acc = fmaf(bhi(hu.z), w[5], acc);
            acc = fmaf(blo(hu.w), w[6], acc); acc = fmaf(bhi(hu.w), w[7], acc);
        }
        vout[b] = acc + vb3[0];
        return;
    }
    const int sl = blockIdx.x >> 5, mb = blockIdx.x & 31;
    const int s  = c * 16 + sl;
    const int tid  = threadIdx.x;
    const int wave = tid >> 6, lane = tid & 63;
    const int quad = lane >> 4, t = lane & 15;

    const __hip_bfloat16* A = h2 + ((size_t)sl * 4096 + (size_t)mb * 128) * 512;
    const __hip_bfloat16* Ap0 = A + ((size_t)(wave * 32 + t)) * 512 + quad * 8;
    const __hip_bfloat16* Ap1 = Ap0 + 16 * 512;
    const __hip_bfloat16* Wp  = w3t + ((size_t)(s * 16 + t)) * 512 + quad * 8;

    f32x4_t acc0 = {}, acc1 = {};
    #pragma unroll
    for (int ks = 0; ks < 16; ++ks) {
        bf16x8_t bq = *(const bf16x8_t*)(Wp  + ks * 32);
        bf16x8_t a0 = *(const bf16x8_t*)(Ap0 + ks * 32);
        bf16x8_t a1 = *(const bf16x8_t*)(Ap1 + ks * 32);
        acc0 = __builtin_amdgcn_mfma_f32_16x16x32_bf16(a0, bq, acc0, 0, 0, 0);
        acc1 = __builtin_amdgcn_mfma_f32_16x16x32_bf16(a1, bq, acc1, 0, 0, 0);
    }

    const int ocol = s * 16 + t;
    const float bias = qb3[ocol];
    const int brow = mb * 128 + wave * 32 + quad * 4;
    #pragma unroll
    for (int r = 0; r < 4; ++r) {
        advout[(size_t)(brow + r) * 512 + ocol]      = acc0[r] + bias;
        advout[(size_t)(brow + 16 + r) * 512 + ocol] = acc1[r] + bias;
    }
}

// ---------------- launch ----------------
extern "C" void kernel_launch(void* const* d_in, const int* in_sizes, int n_in,
                              void* d_out, int out_size, void* d_ws, size_t ws_size,
                              hipStream_t stream) {
    const float* obs      = (const float*)d_in[0];
    const int*   category = (const int*)d_in[1];
    const float* v_w0 = (const float*)d_in[2];
    const float* v_b0 = (const float*)d_in[3];
    const float* v_w1 = (const float*)d_in[4];
    const float* v_b1 = (const float*)d_in[5];
    const float* v_w2 = (const float*)d_in[6];
    const float* v_b2 = (const float*)d_in[7];
    const float* v_w3 = (const float*)d_in[8];
    const float* v_b3 = (const float*)d_in[9];
    const float* q_w0 = (const float*)d_in[10];
    const float* q_b0 = (const float*)d_in[11];
    const float* q_w1 = (const float*)d_in[12];
    const float* q_b1 = (const float*)d_in[13];
    const float* q_w2 = (const float*)d_in[14];
    const float* q_b2 = (const float*)d_in[15];
    const float* q_w3 = (const float*)d_in[16];
    const float* q_b3 = (const float*)d_in[17];

    char* ws = (char*)d_ws;
    __hip_bfloat16* obs_bf = (__hip_bfloat16*)(ws + 0);              // 1 MB
    __hip_bfloat16* w0t    = (__hip_bfloat16*)(ws + 1048576);
    __hip_bfloat16* w1t    = (__hip_bfloat16*)(ws + 1179648);
    __hip_bfloat16* w2t    = (__hip_bfloat16*)(ws + 1703936);
    __hip_bfloat16* w3t    = (__hip_bfloat16*)(ws + 2228224);
    __hip_bfloat16* vw0t   = (__hip_bfloat16*)(ws + 2752512);
    __hip_bfloat16* vw1t   = (__hip_bfloat16*)(ws + 2883584);
    __hip_bfloat16* vw2t   = (__hip_bfloat16*)(ws + 3407872);
    float*          p      = (float*)         (ws + 3932160);        // (4096,512) fp32
    __hip_bfloat16* hva    = (__hip_bfloat16*)(ws + 12320768);       // (4096,512)
    __hip_bfloat16* hvb    = (__hip_bfloat16*)(ws + 16515072);
    float*          acts   = (float*)         (ws + 20709376);       // (131072,8) fp32
    __hip_bfloat16* ha     = (__hip_bfloat16*)(ws + 25165824);       // (65536,512) = 64 MiB
    __hip_bfloat16* hb     = (__hip_bfloat16*)(ws + 92274688);       // 64 MiB, ends 152 MiB

    float* out       = (float*)d_out;
    float* out_value = out;
    float* out_adv   = out + 4096;
    float* out_nbias = out + 4096 + (size_t)B_SZ * 512;

    // 1) all prep in one dispatch (incl. nbias zero)
    prep_kernel<<<12288, 256, 0, stream>>>(
        obs, category, q_w0, q_w1, q_w2, q_w3, v_w0, v_w1, v_w2,
        obs_bf, w0t, w1t, w2t, w3t, vw0t, vw1t, vw2t, acts, out_nbias);

    // 2) P: p = obs@W0a (fp32) || v0: hva = tanh(obs@vW0+b)
    gemm_dual<<<dim3(64, 4), 256, 0, stream>>>(
        obs_bf, w0t, nullptr, p, 128, 0, 32,
        obs_bf, vw0t, v_b0, hva, 128, 1);

    for (int c = 0; c < 2; ++c) {
        const int r0 = c * CHUNK;
        // 3) h0
        h0_kernel<<<1024, 256, 0, stream>>>(p, acts, q_w0, q_b0, ha, r0);
        // 4) G1: hb = tanh(ha@W1+b1) [512 blocks] || c0 only: hvb = tanh(hva@vW1+b)
        if (c == 0)
            gemm_dual<<<dim3(544, 4), 256, 0, stream>>>(
                ha, w1t, q_b1, hb, 512, 1, 512,
                hva, vw1t, v_b1, hvb, 512, 1);
        else
            gemm_dual<<<dim3(512, 4), 256, 0, stream>>>(
                ha, w1t, q_b1, hb, 512, 1, 512,
                ha, w1t, q_b1, hb, 512, 1);
        // 5) G2: ha = tanh(hb@W2+b2) || c0 only: hva = tanh(hvb@vW2+b)
        if (c == 0)
            gemm_dual<<<dim3(544, 4), 256, 0, stream>>>(
                hb, w2t, q_b2, ha, 512, 1, 512,
                hvb, vw2t, v_b2, hva, 512, 1);
        else
            gemm_dual<<<dim3(512, 4), 256, 0, stream>>>(
                hb, w2t, q_b2, ha, 512, 1, 512,
                hb, w2t, q_b2, ha, 512, 1);
        // 6) ADV (+ value head on c0)
        adv_kernel<<<(c == 0 ? 528 : 512), 256, 0, stream>>>(
            ha, w3t, q_b3, out_adv, c, hva, v_w3, v_b3, out_value);
    }
}

// Round 6
// 550.715 us; speedup vs baseline: 1.0175x; 1.0175x over previous
//
#include <hip/hip_runtime.h>
#include <hip/hip_bf16.h>

// Problem constants
#define B_SZ   4096
#define OBS_N  128
#define HID    512
#define CHUNK  65536       // q-MLP rows per chunk (B*S/2): 16 s-values x 4096 b

// Row ordering for the q pipeline is S-MAJOR: global row r = s*4096 + b.
// Dispatch plan (10): prep | P(+v0) | 2 x { h0 | G1(+v1) | G2(+v2) | ADV(+value) }
// GEMM blocks are 1-D, y-fastest (bid>>2 = x, bid&3 = y) so the 4 blocks
// sharing an A x-tile are temporally adjacent -> A-tile L2 reuse.
// LDS staging uses a rot-by-(row>>1) k-chunk swizzle to break the 64B-stride
// bank aliasing of ds_read_b128 (2-way is free, m136).

typedef __bf16 bf16x8_t __attribute__((ext_vector_type(8)));
typedef float  f32x4_t  __attribute__((ext_vector_type(4)));

__device__ inline float fast_tanh(float x) {
    // tanh(x) = 1 - 2/(e^{2x}+1); v_exp_f32 computes 2^x, clamp-free, inf-safe.
    float e = __builtin_amdgcn_exp2f(x * 2.885390081777927f);
    return fmaf(-2.f, __builtin_amdgcn_rcpf(e + 1.f), 1.f);
}

__device__ inline void gld_lds16(const void* g, void* l) {
    __builtin_amdgcn_global_load_lds(
        (const __attribute__((address_space(1))) void*)g,
        (__attribute__((address_space(3))) void*)l, 16, 0, 0);
}

// ---------------- combined prep (obs cast, 7 weight transposes, actions, nbias) ----------------
__global__ __launch_bounds__(256) void prep_kernel(
    const float* __restrict__ obs, const int* __restrict__ category,
    const float* __restrict__ qw0, const float* __restrict__ qw1,
    const float* __restrict__ qw2, const float* __restrict__ qw3,
    const float* __restrict__ vw0, const float* __restrict__ vw1,
    const float* __restrict__ vw2,
    __hip_bfloat16* __restrict__ obs_bf,
    __hip_bfloat16* __restrict__ w0t, __hip_bfloat16* __restrict__ w1t,
    __hip_bfloat16* __restrict__ w2t, __hip_bfloat16* __restrict__ w3t,
    __hip_bfloat16* __restrict__ vw0t, __hip_bfloat16* __restrict__ vw1t,
    __hip_bfloat16* __restrict__ vw2t,
    float* __restrict__ acts, float* __restrict__ nbias)
{
    const int bid = blockIdx.x, tid = threadIdx.x;
    if (bid < 2048) {
        int i = bid * 256 + tid;
        obs_bf[i] = __float2bfloat16(obs[i]);
    } else if (bid < 2560) {   // (512,128) transposes
        const float* src = (bid < 2304) ? qw0 : vw0;
        __hip_bfloat16* dst = (bid < 2304) ? w0t : vw0t;
        int idx = ((bid - 2048) & 255) * 256 + tid;
        int n = idx >> 7, k = idx & 127;
        dst[idx] = __float2bfloat16(src[k * 512 + n]);
    } else if (bid < 7680) {   // (512,512) transposes
        int job = (bid - 2560) >> 10;            // 0..4
        const float* srcs[5] = {qw1, qw2, qw3, vw1, vw2};
        __hip_bfloat16* dsts[5] = {w1t, w2t, w3t, vw1t, vw2t};
        int idx = ((bid - 2560) & 1023) * 256 + tid;
        int n = idx >> 9, k = idx & 511;
        dsts[job][idx] = __float2bfloat16(srcs[job][k * 512 + n]);
    } else if (bid < 11776) {  // actions table, s-major: acts[(s*4096+b)*8+d]
        int t = (bid - 7680) * 256 + tid;
        int d = t & 7;
        int r = t >> 3;
        int b = r & 4095, s = r >> 12;
        int U = (s >> 3) + ((d < (s & 7)) ? 1 : 0);
        float a = 0.f;
        if (U > 0) {
            float w = 0.125f, cum = 0.f;
            for (int j = 0; j < U; ++j) {
                cum += (float)category[b * 32 + j * 8 + d] * w;
                if (j == U - 1) a = -1.f + cum + 0.5f * w;
                w *= 0.0625f;
            }
        }
        acts[t] = a;
    } else {                   // nbias = 0
        int i = (bid - 11776) * 256 + tid;
        nbias[i] = 0.f;
    }
}

// ---------------- dual-job GEMM (m97-style body, 1-D y-fastest grid) ----------------
// Job0 = blocks [0, nb0); job1 the rest. C(M,512) = A(M,K) @ Bt(512,K)^T.
// epi=0: fp32 raw store; epi=1: bf16(tanh(acc+bias)).
__global__ __launch_bounds__(256) void gemm_dual(
    const __hip_bfloat16* __restrict__ A0, const __hip_bfloat16* __restrict__ B0,
    const float* __restrict__ bias0, void* __restrict__ C0, int K0, int epi0, int nb0,
    const __hip_bfloat16* __restrict__ A1, const __hip_bfloat16* __restrict__ B1,
    const float* __restrict__ bias1, void* __restrict__ C1, int K1, int epi1)
{
    __shared__ __hip_bfloat16 As[128 * 32];
    __shared__ __hip_bfloat16 Bs[128 * 32];

    const __hip_bfloat16 *A, *Bt;
    const float* bias;
    void* Cout;
    int K, epi, tb;
    if ((int)blockIdx.x < nb0) {
        A = A0; Bt = B0; bias = bias0; Cout = C0; K = K0; epi = epi0; tb = blockIdx.x;
    } else {
        A = A1; Bt = B1; bias = bias1; Cout = C1; K = K1; epi = epi1; tb = blockIdx.x - nb0;
    }
    const long m0 = (long)(tb >> 2) * 128;   // y-fastest: adjacent blocks share A-tile
    const int  n0 = (tb & 3) * 128;

    const int tid  = threadIdx.x;
    const int wave = tid >> 6, lane = tid & 63;
    const int quad = lane >> 4, t = lane & 15;
    const int wr = wave >> 1, wc = wave & 1;

    f32x4_t acc[4][4] = {};

    const int lrow  = lane >> 2;                          // 0..15 row within 16-group
    const int lkoff = (((lane & 3) + (lane >> 3)) & 3) * 8;  // swizzled k-chunk fetch

    const __hip_bfloat16* Ag0 = A  + (m0 + wave * 32 +      lrow) * (long)K + lkoff;
    const __hip_bfloat16* Ag1 = A  + (m0 + wave * 32 + 16 + lrow) * (long)K + lkoff;
    const __hip_bfloat16* Bg0 = Bt + (long)(n0 + wave * 32 +      lrow) * K + lkoff;
    const __hip_bfloat16* Bg1 = Bt + (long)(n0 + wave * 32 + 16 + lrow) * K + lkoff;
    __hip_bfloat16* AsB0 = &As[(wave * 32) * 32];
    __hip_bfloat16* AsB1 = &As[(wave * 32 + 16) * 32];
    __hip_bfloat16* BsB0 = &Bs[(wave * 32) * 32];
    __hip_bfloat16* BsB1 = &Bs[(wave * 32 + 16) * 32];

    const int slot = ((quad - (t >> 1)) & 3) * 8;  // swizzled read slot

    for (int k0 = 0; k0 < K; k0 += 32) {
        gld_lds16(Ag0 + k0, AsB0);
        gld_lds16(Ag1 + k0, AsB1);
        gld_lds16(Bg0 + k0, BsB0);
        gld_lds16(Bg1 + k0, BsB1);
        __syncthreads();
        bf16x8_t af[4], bfr[4];
        #pragma unroll
        for (int i = 0; i < 4; ++i)
            af[i] = *(const bf16x8_t*)&As[(wr * 64 + i * 16 + t) * 32 + slot];
        #pragma unroll
        for (int j = 0; j < 4; ++j)
            bfr[j] = *(const bf16x8_t*)&Bs[(wc * 64 + j * 16 + t) * 32 + slot];
        #pragma unroll
        for (int i = 0; i < 4; ++i)
            #pragma unroll
            for (int j = 0; j < 4; ++j)
                acc[i][j] = __builtin_amdgcn_mfma_f32_16x16x32_bf16(af[i], bfr[j], acc[i][j], 0, 0, 0);
        __syncthreads();
    }

    #pragma unroll
    for (int i = 0; i < 4; ++i) {
        const long rbase = m0 + wr * 64 + i * 16 + quad * 4;
        #pragma unroll
        for (int j = 0; j < 4; ++j) {
            const int col = n0 + wc * 64 + j * 16 + t;
            #pragma unroll
            for (int r = 0; r < 4; ++r) {
                float v = acc[i][j][r];
                if (epi) {
                    v = fast_tanh(v + bias[col]);
                    ((__hip_bfloat16*)Cout)[(rbase + r) * 512 + col] = __float2bfloat16(v);
                } else {
                    ((float*)Cout)[(rbase + r) * 512 + col] = v;
                }
            }
        }
    }
}

// ---------------- q layer 0: h0 = tanh(p[b] + acts(r)@W0b + b0) ----------------
__global__ __launch_bounds__(256) void h0_kernel(
    const float* __restrict__ p,         // (4096,512) fp32 = obs @ W0[:128]
    const float* __restrict__ acts,      // (131072,8) fp32 s-major
    const float* __restrict__ qw0,       // (136,512) fp32 (rows 128..135 = action part)
    const float* __restrict__ qb0,       // (512)
    __hip_bfloat16* __restrict__ h0,     // (CHUNK,512)
    int r0)
{
    const int wave = threadIdx.x >> 6, lane = threadIdx.x & 63;
    const int col0 = lane * 8;

    float w[8][8], bb[8];
    #pragma unroll
    for (int d = 0; d < 8; ++d) {
        float4 u0 = *(const float4*)&qw0[(128 + d) * 512 + col0];
        float4 u1 = *(const float4*)&qw0[(128 + d) * 512 + col0 + 4];
        w[d][0] = u0.x; w[d][1] = u0.y; w[d][2] = u0.z; w[d][3] = u0.w;
        w[d][4] = u1.x; w[d][5] = u1.y; w[d][6] = u1.z; w[d][7] = u1.w;
    }
    {
        float4 b0 = *(const float4*)&qb0[col0];
        float4 b1 = *(const float4*)&qb0[col0 + 4];
        bb[0] = b0.x; bb[1] = b0.y; bb[2] = b0.z; bb[3] = b0.w;
        bb[4] = b1.x; bb[5] = b1.y; bb[6] = b1.z; bb[7] = b1.w;
    }

    #pragma unroll 2
    for (int rr = 0; rr < 16; ++rr) {
        const int lr = blockIdx.x * 64 + wave * 16 + rr;
        const int b  = lr & 4095;
        const float4* pp = (const float4*)&p[(size_t)b * 512 + col0];
        float4 p0 = pp[0], p1 = pp[1];
        const float4* ap = (const float4*)&acts[(size_t)(r0 + lr) * 8];
        float4 a0 = ap[0], a1 = ap[1];
        float a[8] = {a0.x, a0.y, a0.z, a0.w, a1.x, a1.y, a1.z, a1.w};
        float v[8] = {p0.x + bb[0], p0.y + bb[1], p0.z + bb[2], p0.w + bb[3],
                      p1.x + bb[4], p1.y + bb[5], p1.z + bb[6], p1.w + bb[7]};
        #pragma unroll
        for (int d = 0; d < 8; ++d)
            #pragma unroll
            for (int cc = 0; cc < 8; ++cc)
                v[cc] = fmaf(a[d], w[d][cc], v[cc]);
        union { bf16x8_t vec; __hip_bfloat16 e[8]; } o;
        #pragma unroll
        for (int cc = 0; cc < 8; ++cc)
            o.e[cc] = __float2bfloat16(fast_tanh(v[cc]));
        *(bf16x8_t*)&h0[(size_t)lr * 512 + col0] = o.vec;
    }
}

// ---------------- q layer 3 diag (MFMA) + optional value-head blocks ----------------
__device__ inline float blo(unsigned u) { return __uint_as_float(u << 16); }
__device__ inline float bhi(unsigned u) { return __uint_as_float(u & 0xffff0000u); }

__global__ __launch_bounds__(256) void adv_kernel(
    const __hip_bfloat16* __restrict__ h2,   // (CHUNK,512) s-major
    const __hip_bfloat16* __restrict__ w3t,  // (512,512): [out][k]
    const float* __restrict__ qb3,
    float* __restrict__ advout,              // (4096,512) at d_out+4096
    int c,                                   // chunk index
    const __hip_bfloat16* __restrict__ hv2,  // (4096,512) v hidden
    const float* __restrict__ vw3, const float* __restrict__ vb3,
    float* __restrict__ vout)
{
    if ((int)blockIdx.x >= 512) {
        // value head: 16 blocks cover 4096 rows
        int b = ((int)blockIdx.x - 512) * 256 + threadIdx.x;
        const uint4* h = (const uint4*)(hv2 + (size_t)b * 512);
        float acc = 0.f;
        for (int i = 0; i < 64; ++i) {
            uint4 hu = h[i];
            const float* w = vw3 + i * 8;
            acc = fmaf(blo(hu.x), w[0], acc); acc = fmaf(bhi(hu.x), w[1], acc);
            acc = fmaf(blo(hu.y), w[2], acc); acc = fmaf(bhi(hu.y), w[3], acc);
            acc = fmaf(blo(hu.z), w[4], acc); acc = fmaf(bhi(hu.z), w[5], acc);
            acc = fmaf(blo(hu.w), w[6], acc); acc = fmaf(bhi(hu.w), w[7], acc);
        }
        vout[b] = acc + vb3[0];
        return;
    }
    const int sl = blockIdx.x >> 5, mb = blockIdx.x & 31;
    const int s  = c * 16 + sl;
    const int tid  = threadIdx.x;
    const int wave = tid >> 6, lane = tid & 63;
    const int quad = lane >> 4, t = lane & 15;

    const __hip_bfloat16* A = h2 + ((size_t)sl * 4096 + (size_t)mb * 128) * 512;
    const __hip_bfloat16* Ap0 = A + ((size_t)(wave * 32 + t)) * 512 + quad * 8;
    const __hip_bfloat16* Ap1 = Ap0 + 16 * 512;
    const __hip_bfloat16* Wp  = w3t + ((size_t)(s * 16 + t)) * 512 + quad * 8;

    f32x4_t acc0 = {}, acc1 = {};
    #pragma unroll
    for (int ks = 0; ks < 16; ++ks) {
        bf16x8_t bq = *(const bf16x8_t*)(Wp  + ks * 32);
        bf16x8_t a0 = *(const bf16x8_t*)(Ap0 + ks * 32);
        bf16x8_t a1 = *(const bf16x8_t*)(Ap1 + ks * 32);
        acc0 = __builtin_amdgcn_mfma_f32_16x16x32_bf16(a0, bq, acc0, 0, 0, 0);
        acc1 = __builtin_amdgcn_mfma_f32_16x16x32_bf16(a1, bq, acc1, 0, 0, 0);
    }

    const int ocol = s * 16 + t;
    const float bias = qb3[ocol];
    const int brow = mb * 128 + wave * 32 + quad * 4;
    #pragma unroll
    for (int r = 0; r < 4; ++r) {
        advout[(size_t)(brow + r) * 512 + ocol]      = acc0[r] + bias;
        advout[(size_t)(brow + 16 + r) * 512 + ocol] = acc1[r] + bias;
    }
}

// ---------------- launch ----------------
extern "C" void kernel_launch(void* const* d_in, const int* in_sizes, int n_in,
                              void* d_out, int out_size, void* d_ws, size_t ws_size,
                              hipStream_t stream) {
    const float* obs      = (const float*)d_in[0];
    const int*   category = (const int*)d_in[1];
    const float* v_w0 = (const float*)d_in[2];
    const float* v_b0 = (const float*)d_in[3];
    const float* v_w1 = (const float*)d_in[4];
    const float* v_b1 = (const float*)d_in[5];
    const float* v_w2 = (const float*)d_in[6];
    const float* v_b2 = (const float*)d_in[7];
    const float* v_w3 = (const float*)d_in[8];
    const float* v_b3 = (const float*)d_in[9];
    const float* q_w0 = (const float*)d_in[10];
    const float* q_b0 = (const float*)d_in[11];
    const float* q_w1 = (const float*)d_in[12];
    const float* q_b1 = (const float*)d_in[13];
    const float* q_w2 = (const float*)d_in[14];
    const float* q_b2 = (const float*)d_in[15];
    const float* q_w3 = (const float*)d_in[16];
    const float* q_b3 = (const float*)d_in[17];

    char* ws = (char*)d_ws;
    __hip_bfloat16* obs_bf = (__hip_bfloat16*)(ws + 0);              // 1 MB
    __hip_bfloat16* w0t    = (__hip_bfloat16*)(ws + 1048576);
    __hip_bfloat16* w1t    = (__hip_bfloat16*)(ws + 1179648);
    __hip_bfloat16* w2t    = (__hip_bfloat16*)(ws + 1703936);
    __hip_bfloat16* w3t    = (__hip_bfloat16*)(ws + 2228224);
    __hip_bfloat16* vw0t   = (__hip_bfloat16*)(ws + 2752512);
    __hip_bfloat16* vw1t   = (__hip_bfloat16*)(ws + 2883584);
    __hip_bfloat16* vw2t   = (__hip_bfloat16*)(ws + 3407872);
    float*          p      = (float*)         (ws + 3932160);        // (4096,512) fp32
    __hip_bfloat16* hva    = (__hip_bfloat16*)(ws + 12320768);       // (4096,512)
    __hip_bfloat16* hvb    = (__hip_bfloat16*)(ws + 16515072);
    float*          acts   = (float*)         (ws + 20709376);       // (131072,8) fp32
    __hip_bfloat16* ha     = (__hip_bfloat16*)(ws + 25165824);       // (65536,512) = 64 MiB
    __hip_bfloat16* hb     = (__hip_bfloat16*)(ws + 92274688);       // 64 MiB, ends 152 MiB

    float* out       = (float*)d_out;
    float* out_value = out;
    float* out_adv   = out + 4096;
    float* out_nbias = out + 4096 + (size_t)B_SZ * 512;

    // 1) all prep in one dispatch (incl. nbias zero)
    prep_kernel<<<12288, 256, 0, stream>>>(
        obs, category, q_w0, q_w1, q_w2, q_w3, v_w0, v_w1, v_w2,
        obs_bf, w0t, w1t, w2t, w3t, vw0t, vw1t, vw2t, acts, out_nbias);

    // 2) P: p = obs@W0a (fp32) || v0: hva = tanh(obs@vW0+b)
    gemm_dual<<<256, 256, 0, stream>>>(
        obs_bf, w0t, nullptr, p, 128, 0, 128,
        obs_bf, vw0t, v_b0, hva, 128, 1);

    for (int c = 0; c < 2; ++c) {
        const int r0 = c * CHUNK;
        // 3) h0
        h0_kernel<<<1024, 256, 0, stream>>>(p, acts, q_w0, q_b0, ha, r0);
        // 4) G1: hb = tanh(ha@W1+b1) [2048 blocks] || c0 only: hvb = tanh(hva@vW1+b)
        if (c == 0)
            gemm_dual<<<2176, 256, 0, stream>>>(
                ha, w1t, q_b1, hb, 512, 1, 2048,
                hva, vw1t, v_b1, hvb, 512, 1);
        else
            gemm_dual<<<2048, 256, 0, stream>>>(
                ha, w1t, q_b1, hb, 512, 1, 2048,
                ha, w1t, q_b1, hb, 512, 1);
        // 5) G2: ha = tanh(hb@W2+b2) || c0 only: hva = tanh(hvb@vW2+b)
        if (c == 0)
            gemm_dual<<<2176, 256, 0, stream>>>(
                hb, w2t, q_b2, ha, 512, 1, 2048,
                hvb, vw2t, v_b2, hva, 512, 1);
        else
            gemm_dual<<<2048, 256, 0, stream>>>(
                hb, w2t, q_b2, ha, 512, 1, 2048,
                hb, w2t, q_b2, ha, 512, 1);
        // 6) ADV (+ value head on c0)
        adv_kernel<<<(c == 0 ? 528 : 512), 256, 0, stream>>>(
            ha, w3t, q_b3, out_adv, c, hva, v_w3, v_b3, out_value);
    }
}

// Round 7
// 489.844 us; speedup vs baseline: 1.1439x; 1.1243x over previous
//
#include <hip/hip_runtime.h>
#include <hip/hip_bf16.h>

// Problem constants
#define B_SZ   4096
#define OBS_N  128
#define HID    512

// S-MAJOR q rows: r = s*4096 + b. Fused kernel: block = 64 rows (one s, 64 b's),
// all 3 hidden layers chained through a 64KB LDS activation buffer (XOR-swizzled),
// W read direct global->VGPR (L2-resident). 3 dispatches: prep | P | fused.

typedef __bf16 bf16x8_t __attribute__((ext_vector_type(8)));
typedef float  f32x4_t  __attribute__((ext_vector_type(4)));

__device__ inline float fast_tanh(float x) {
    // tanh(x) = 1 - 2/(e^{2x}+1); v_exp_f32 computes 2^x, clamp-free, inf-safe.
    float e = __builtin_amdgcn_exp2f(x * 2.885390081777927f);
    return fmaf(-2.f, __builtin_amdgcn_rcpf(e + 1.f), 1.f);
}

__device__ inline void gld_lds16(const void* g, void* l) {
    __builtin_amdgcn_global_load_lds(
        (const __attribute__((address_space(1))) void*)g,
        (__attribute__((address_space(3))) void*)l, 16, 0, 0);
}

// hs element (row, col) lives at row*512 + phys(chunk)*8 + col%8,
// phys = (c & ~7) | ((c ^ (row&7)) & 7), c = col/8. 2-way-or-free banks.
__device__ inline int hs_off(int row, int col) {
    int c = col >> 3;
    int phys = (c & ~7) | ((c ^ (row & 7)) & 7);
    return row * 512 + phys * 8 + (col & 7);
}

// ---------------- combined prep (obs cast, 7 weight transposes, actions, nbias) ----------------
__global__ __launch_bounds__(256) void prep_kernel(
    const float* __restrict__ obs, const int* __restrict__ category,
    const float* __restrict__ qw0, const float* __restrict__ qw1,
    const float* __restrict__ qw2, const float* __restrict__ qw3,
    const float* __restrict__ vw0, const float* __restrict__ vw1,
    const float* __restrict__ vw2,
    __hip_bfloat16* __restrict__ obs_bf,
    __hip_bfloat16* __restrict__ w0t, __hip_bfloat16* __restrict__ w1t,
    __hip_bfloat16* __restrict__ w2t, __hip_bfloat16* __restrict__ w3t,
    __hip_bfloat16* __restrict__ vw0t, __hip_bfloat16* __restrict__ vw1t,
    __hip_bfloat16* __restrict__ vw2t,
    float* __restrict__ acts, float* __restrict__ nbias)
{
    const int bid = blockIdx.x, tid = threadIdx.x;
    if (bid < 2048) {
        int i = bid * 256 + tid;
        obs_bf[i] = __float2bfloat16(obs[i]);
    } else if (bid < 2560) {   // (512,128) transposes
        const float* src = (bid < 2304) ? qw0 : vw0;
        __hip_bfloat16* dst = (bid < 2304) ? w0t : vw0t;
        int idx = ((bid - 2048) & 255) * 256 + tid;
        int n = idx >> 7, k = idx & 127;
        dst[idx] = __float2bfloat16(src[k * 512 + n]);
    } else if (bid < 7680) {   // (512,512) transposes
        int job = (bid - 2560) >> 10;            // 0..4
        const float* srcs[5] = {qw1, qw2, qw3, vw1, vw2};
        __hip_bfloat16* dsts[5] = {w1t, w2t, w3t, vw1t, vw2t};
        int idx = ((bid - 2560) & 1023) * 256 + tid;
        int n = idx >> 9, k = idx & 511;
        dsts[job][idx] = __float2bfloat16(srcs[job][k * 512 + n]);
    } else if (bid < 11776) {  // actions table, s-major: acts[(s*4096+b)*8+d]
        int t = (bid - 7680) * 256 + tid;
        int d = t & 7;
        int r = t >> 3;
        int b = r & 4095, s = r >> 12;
        int U = (s >> 3) + ((d < (s & 7)) ? 1 : 0);
        float a = 0.f;
        if (U > 0) {
            float w = 0.125f, cum = 0.f;
            for (int j = 0; j < U; ++j) {
                cum += (float)category[b * 32 + j * 8 + d] * w;
                if (j == U - 1) a = -1.f + cum + 0.5f * w;
                w *= 0.0625f;
            }
        }
        acts[t] = a;
    } else {                   // nbias = 0
        int i = (bid - 11776) * 256 + tid;
        nbias[i] = 0.f;
    }
}

// ---------------- dual-job GEMM (m97-style, used only for the small P dispatch) ----------------
// epi=0: fp32 raw; epi=1: bf16(tanh(acc+bias)); epi=2: bf16 raw.
__global__ __launch_bounds__(256) void gemm_dual(
    const __hip_bfloat16* __restrict__ A0, const __hip_bfloat16* __restrict__ B0,
    const float* __restrict__ bias0, void* __restrict__ C0, int K0, int epi0, int nb0,
    const __hip_bfloat16* __restrict__ A1, const __hip_bfloat16* __restrict__ B1,
    const float* __restrict__ bias1, void* __restrict__ C1, int K1, int epi1)
{
    __shared__ __hip_bfloat16 As[128 * 32];
    __shared__ __hip_bfloat16 Bs[128 * 32];

    const __hip_bfloat16 *A, *Bt;
    const float* bias;
    void* Cout;
    int K, epi, tb;
    if ((int)blockIdx.x < nb0) {
        A = A0; Bt = B0; bias = bias0; Cout = C0; K = K0; epi = epi0; tb = blockIdx.x;
    } else {
        A = A1; Bt = B1; bias = bias1; Cout = C1; K = K1; epi = epi1; tb = blockIdx.x - nb0;
    }
    const long m0 = (long)(tb >> 2) * 128;
    const int  n0 = (tb & 3) * 128;

    const int tid  = threadIdx.x;
    const int wave = tid >> 6, lane = tid & 63;
    const int quad = lane >> 4, t = lane & 15;
    const int wr = wave >> 1, wc = wave & 1;

    f32x4_t acc[4][4] = {};

    const int lrow  = lane >> 2;
    const int lkoff = (((lane & 3) + (lane >> 3)) & 3) * 8;

    const __hip_bfloat16* Ag0 = A  + (m0 + wave * 32 +      lrow) * (long)K + lkoff;
    const __hip_bfloat16* Ag1 = A  + (m0 + wave * 32 + 16 + lrow) * (long)K + lkoff;
    const __hip_bfloat16* Bg0 = Bt + (long)(n0 + wave * 32 +      lrow) * K + lkoff;
    const __hip_bfloat16* Bg1 = Bt + (long)(n0 + wave * 32 + 16 + lrow) * K + lkoff;
    __hip_bfloat16* AsB0 = &As[(wave * 32) * 32];
    __hip_bfloat16* AsB1 = &As[(wave * 32 + 16) * 32];
    __hip_bfloat16* BsB0 = &Bs[(wave * 32) * 32];
    __hip_bfloat16* BsB1 = &Bs[(wave * 32 + 16) * 32];

    const int slot = ((quad - (t >> 1)) & 3) * 8;

    for (int k0 = 0; k0 < K; k0 += 32) {
        gld_lds16(Ag0 + k0, AsB0);
        gld_lds16(Ag1 + k0, AsB1);
        gld_lds16(Bg0 + k0, BsB0);
        gld_lds16(Bg1 + k0, BsB1);
        __syncthreads();
        bf16x8_t af[4], bfr[4];
        #pragma unroll
        for (int i = 0; i < 4; ++i)
            af[i] = *(const bf16x8_t*)&As[(wr * 64 + i * 16 + t) * 32 + slot];
        #pragma unroll
        for (int j = 0; j < 4; ++j)
            bfr[j] = *(const bf16x8_t*)&Bs[(wc * 64 + j * 16 + t) * 32 + slot];
        #pragma unroll
        for (int i = 0; i < 4; ++i)
            #pragma unroll
            for (int j = 0; j < 4; ++j)
                acc[i][j] = __builtin_amdgcn_mfma_f32_16x16x32_bf16(af[i], bfr[j], acc[i][j], 0, 0, 0);
        __syncthreads();
    }

    #pragma unroll
    for (int i = 0; i < 4; ++i) {
        const long rbase = m0 + wr * 64 + i * 16 + quad * 4;
        #pragma unroll
        for (int j = 0; j < 4; ++j) {
            const int col = n0 + wc * 64 + j * 16 + t;
            #pragma unroll
            for (int r = 0; r < 4; ++r) {
                float v = acc[i][j][r];
                if (epi == 1) {
                    v = fast_tanh(v + bias[col]);
                    ((__hip_bfloat16*)Cout)[(rbase + r) * 512 + col] = __float2bfloat16(v);
                } else if (epi == 2) {
                    ((__hip_bfloat16*)Cout)[(rbase + r) * 512 + col] = __float2bfloat16(v);
                } else {
                    ((float*)Cout)[(rbase + r) * 512 + col] = v;
                }
            }
        }
    }
}

// ---------------- fused MLP layer: hs(64x512) = tanh(hs @ W^T + bias) ----------------
// Wave w computes cols [w*128, w*128+128), rows 0..63. B-frags direct from global (L2).
__device__ inline void mfma_layer(
    __hip_bfloat16* hs, const __hip_bfloat16* __restrict__ W,
    const float* __restrict__ bias, int w, int lane)
{
    const int quad = lane >> 4, t = lane & 15;
    const int n0w = w * 128;
    f32x4_t acc[4][8] = {};
    #pragma unroll 2
    for (int kc = 0; kc < 16; ++kc) {
        bf16x8_t a[4];
        const int craw = kc * 4 + quad;
        const int phys = (craw & ~7) | ((craw ^ (t & 7)) & 7);
        #pragma unroll
        for (int rt = 0; rt < 4; ++rt)
            a[rt] = *(const bf16x8_t*)&hs[(rt * 16 + t) * 512 + phys * 8];
        #pragma unroll
        for (int j = 0; j < 8; ++j) {
            bf16x8_t bq = *(const bf16x8_t*)&W[(size_t)(n0w + j * 16 + t) * 512 + kc * 32 + quad * 8];
            #pragma unroll
            for (int rt = 0; rt < 4; ++rt)
                acc[rt][j] = __builtin_amdgcn_mfma_f32_16x16x32_bf16(a[rt], bq, acc[rt][j], 0, 0, 0);
        }
    }
    __syncthreads();   // all reads of hs complete
    float bl[8];
    #pragma unroll
    for (int j = 0; j < 8; ++j) bl[j] = bias[n0w + j * 16 + t];
    #pragma unroll
    for (int rt = 0; rt < 4; ++rt)
        #pragma unroll
        for (int j = 0; j < 8; ++j)
            #pragma unroll
            for (int rr = 0; rr < 4; ++rr) {
                int row = rt * 16 + quad * 4 + rr;
                int col = n0w + j * 16 + t;
                float vv = fast_tanh(acc[rt][j][rr] + bl[j]);
                hs[hs_off(row, col)] = __float2bfloat16(vv);
            }
    __syncthreads();   // hs now holds the layer output
}

// ---------------- fused MLP kernel: q-blocks [0,2048), v-blocks [2048,2112) ----------------
__global__ __launch_bounds__(256, 2) void fused_kernel(
    const __hip_bfloat16* __restrict__ p_bf,   // (4096,512) = obs@W0a, raw bf16
    const __hip_bfloat16* __restrict__ pv_bf,  // (4096,512) = obs@vW0, raw bf16
    const float* __restrict__ acts,            // (131072,8) s-major
    const float* __restrict__ qw0, const float* __restrict__ qb0,
    const __hip_bfloat16* __restrict__ w1t, const float* __restrict__ qb1,
    const __hip_bfloat16* __restrict__ w2t, const float* __restrict__ qb2,
    const __hip_bfloat16* __restrict__ w3t, const float* __restrict__ qb3,
    float* __restrict__ advout,
    const float* __restrict__ vb0,
    const __hip_bfloat16* __restrict__ vw1t, const float* __restrict__ vb1,
    const __hip_bfloat16* __restrict__ vw2t, const float* __restrict__ vb2,
    const float* __restrict__ vw3, const float* __restrict__ vb3,
    float* __restrict__ vout)
{
    __shared__ __hip_bfloat16 hs[64 * 512];   // 64 KB
    const int bid = blockIdx.x;
    const int tid = threadIdx.x;
    const int w = tid >> 6, lane = tid & 63;
    const int quad = lane >> 4, t = lane & 15;
    const bool is_q = bid < 2048;
    const int s  = is_q ? (bid >> 6) : 0;
    const int mb = is_q ? (bid & 63) : (bid - 2048);

    // ---- phase 0: layer-0 activations into hs (pure VALU) ----
    {
        const int col0 = lane * 8;
        float bb[8];
        {
            const float* bsrc = is_q ? qb0 : vb0;
            float4 b0 = *(const float4*)&bsrc[col0];
            float4 b1 = *(const float4*)&bsrc[col0 + 4];
            bb[0] = b0.x; bb[1] = b0.y; bb[2] = b0.z; bb[3] = b0.w;
            bb[4] = b1.x; bb[5] = b1.y; bb[6] = b1.z; bb[7] = b1.w;
        }
        if (is_q) {
            float wr[8][8];
            #pragma unroll
            for (int d = 0; d < 8; ++d) {
                float4 u0 = *(const float4*)&qw0[(128 + d) * 512 + col0];
                float4 u1 = *(const float4*)&qw0[(128 + d) * 512 + col0 + 4];
                wr[d][0] = u0.x; wr[d][1] = u0.y; wr[d][2] = u0.z; wr[d][3] = u0.w;
                wr[d][4] = u1.x; wr[d][5] = u1.y; wr[d][6] = u1.z; wr[d][7] = u1.w;
            }
            for (int i = 0; i < 16; ++i) {
                const int row = w * 16 + i;
                const int b = mb * 64 + row;
                const long r = (long)s * 4096 + b;
                union { bf16x8_t vec; __hip_bfloat16 e[8]; } pu;
                pu.vec = *(const bf16x8_t*)&p_bf[(size_t)b * 512 + col0];
                float4 a0 = *(const float4*)&acts[r * 8];
                float4 a1 = *(const float4*)&acts[r * 8 + 4];
                float a[8] = {a0.x, a0.y, a0.z, a0.w, a1.x, a1.y, a1.z, a1.w};
                float v[8];
                #pragma unroll
                for (int cc = 0; cc < 8; ++cc) v[cc] = __bfloat162float(pu.e[cc]) + bb[cc];
                #pragma unroll
                for (int d = 0; d < 8; ++d)
                    #pragma unroll
                    for (int cc = 0; cc < 8; ++cc)
                        v[cc] = fmaf(a[d], wr[d][cc], v[cc]);
                union { bf16x8_t vec; __hip_bfloat16 e[8]; } o;
                #pragma unroll
                for (int cc = 0; cc < 8; ++cc) o.e[cc] = __float2bfloat16(fast_tanh(v[cc]));
                const int phys = (lane & ~7) | ((lane ^ (row & 7)) & 7);
                *(bf16x8_t*)&hs[row * 512 + phys * 8] = o.vec;
            }
        } else {
            for (int i = 0; i < 16; ++i) {
                const int row = w * 16 + i;
                const int b = mb * 64 + row;
                union { bf16x8_t vec; __hip_bfloat16 e[8]; } pu;
                pu.vec = *(const bf16x8_t*)&pv_bf[(size_t)b * 512 + col0];
                union { bf16x8_t vec; __hip_bfloat16 e[8]; } o;
                #pragma unroll
                for (int cc = 0; cc < 8; ++cc)
                    o.e[cc] = __float2bfloat16(fast_tanh(__bfloat162float(pu.e[cc]) + bb[cc]));
                const int phys = (lane & ~7) | ((lane ^ (row & 7)) & 7);
                *(bf16x8_t*)&hs[row * 512 + phys * 8] = o.vec;
            }
        }
    }
    __syncthreads();

    // ---- layers 1 and 2 ----
    mfma_layer(hs, is_q ? w1t : vw1t, is_q ? qb1 : vb1, w, lane);
    mfma_layer(hs, is_q ? w2t : vw2t, is_q ? qb2 : vb2, w, lane);

    // ---- layer 3 ----
    if (is_q) {
        // diag slice: 64 rows x 16 cols (cols s*16..s*16+16); wave w -> row-tile w
        f32x4_t acc = {};
        #pragma unroll 4
        for (int kc = 0; kc < 16; ++kc) {
            const int craw = kc * 4 + quad;
            const int phys = (craw & ~7) | ((craw ^ (t & 7)) & 7);
            bf16x8_t a = *(const bf16x8_t*)&hs[(w * 16 + t) * 512 + phys * 8];
            bf16x8_t bq = *(const bf16x8_t*)&w3t[(size_t)(s * 16 + t) * 512 + kc * 32 + quad * 8];
            acc = __builtin_amdgcn_mfma_f32_16x16x32_bf16(a, bq, acc, 0, 0, 0);
        }
        const float bias3 = qb3[s * 16 + t];
        #pragma unroll
        for (int rr = 0; rr < 4; ++rr) {
            const int row = w * 16 + quad * 4 + rr;
            const int b = mb * 64 + row;
            advout[(size_t)b * 512 + s * 16 + t] = acc[rr] + bias3;
        }
    } else {
        // value head: row = tid>>2 (0..63), seg = tid&3 sums 128 elems
        const int row = tid >> 2, seg = tid & 3;
        float sum = 0.f;
        for (int k = seg * 128; k < seg * 128 + 128; ++k)
            sum += __bfloat162float(hs[hs_off(row, k)]) * vw3[k];
        sum += __shfl_xor(sum, 1);
        sum += __shfl_xor(sum, 2);
        if (seg == 0) vout[mb * 64 + row] = sum + vb3[0];
    }
}

// ---------------- launch ----------------
extern "C" void kernel_launch(void* const* d_in, const int* in_sizes, int n_in,
                              void* d_out, int out_size, void* d_ws, size_t ws_size,
                              hipStream_t stream) {
    const float* obs      = (const float*)d_in[0];
    const int*   category = (const int*)d_in[1];
    const float* v_w0 = (const float*)d_in[2];
    const float* v_b0 = (const float*)d_in[3];
    const float* v_w1 = (const float*)d_in[4];
    const float* v_b1 = (const float*)d_in[5];
    const float* v_w2 = (const float*)d_in[6];
    const float* v_b2 = (const float*)d_in[7];
    const float* v_w3 = (const float*)d_in[8];
    const float* v_b3 = (const float*)d_in[9];
    const float* q_w0 = (const float*)d_in[10];
    const float* q_b0 = (const float*)d_in[11];
    const float* q_w1 = (const float*)d_in[12];
    const float* q_b1 = (const float*)d_in[13];
    const float* q_w2 = (const float*)d_in[14];
    const float* q_b2 = (const float*)d_in[15];
    const float* q_w3 = (const float*)d_in[16];
    const float* q_b3 = (const float*)d_in[17];

    char* ws = (char*)d_ws;
    __hip_bfloat16* obs_bf = (__hip_bfloat16*)(ws + 0);              // 1 MB
    __hip_bfloat16* w0t    = (__hip_bfloat16*)(ws + 1048576);        // (512,128)
    __hip_bfloat16* vw0t   = (__hip_bfloat16*)(ws + 1179648);        // (512,128)
    __hip_bfloat16* w1t    = (__hip_bfloat16*)(ws + 1310720);        // (512,512)
    __hip_bfloat16* w2t    = (__hip_bfloat16*)(ws + 1835008);
    __hip_bfloat16* w3t    = (__hip_bfloat16*)(ws + 2359296);
    __hip_bfloat16* vw1t   = (__hip_bfloat16*)(ws + 2883584);
    __hip_bfloat16* vw2t   = (__hip_bfloat16*)(ws + 3407872);
    float*          acts   = (float*)         (ws + 3932160);        // (131072,8) fp32, 4 MB
    __hip_bfloat16* p_bf   = (__hip_bfloat16*)(ws + 8126464);        // (4096,512) bf16
    __hip_bfloat16* pv_bf  = (__hip_bfloat16*)(ws + 12320768);       // (4096,512) bf16

    float* out       = (float*)d_out;
    float* out_value = out;
    float* out_adv   = out + 4096;
    float* out_nbias = out + 4096 + (size_t)B_SZ * 512;

    // 1) all prep in one dispatch (incl. nbias zero)
    prep_kernel<<<12288, 256, 0, stream>>>(
        obs, category, q_w0, q_w1, q_w2, q_w3, v_w0, v_w1, v_w2,
        obs_bf, w0t, w1t, w2t, w3t, vw0t, vw1t, vw2t, acts, out_nbias);

    // 2) P: p_bf = obs@W0a || pv_bf = obs@vW0 (both raw bf16)
    gemm_dual<<<256, 256, 0, stream>>>(
        obs_bf, w0t, nullptr, p_bf, 128, 2, 128,
        obs_bf, vw0t, nullptr, pv_bf, 128, 2);

    // 3) fused q+v MLP (2048 q-blocks + 64 v-blocks)
    fused_kernel<<<2112, 256, 0, stream>>>(
        p_bf, pv_bf, acts, q_w0, q_b0, w1t, q_b1, w2t, q_b2, w3t, q_b3, out_adv,
        v_b0, vw1t, v_b1, vw2t, v_b2, v_w3, v_b3, out_value);
}

// Round 8
// 421.355 us; speedup vs baseline: 1.3299x; 1.1625x over previous
//
#include <hip/hip_runtime.h>
#include <hip/hip_bf16.h>

// Problem constants
#define B_SZ   4096
#define OBS_N  128
#define HID    512

// S-MAJOR q rows: r = s*4096 + b. Fused kernel: block = 64 rows (one s, 64 b's),
// 512 threads (8 waves), all 3 hidden layers chained through a 64KB LDS buffer
// (XOR-swizzled chunks). Layers use D = W·hs (out x batch) so the epilogue
// writes 4 consecutive out-cols per thread as one ds_write_b64.
// Wave owns 64 out-cols -> acc[4][4] = 64 VGPR, launch_bounds(512,4) => <=128 regs,
// 2 blocks/CU. 3 dispatches: prep | P | fused.

typedef __bf16 bf16x8_t __attribute__((ext_vector_type(8)));
typedef float  f32x4_t  __attribute__((ext_vector_type(4)));

__device__ inline float fast_tanh(float x) {
    // tanh(x) = 1 - 2/(e^{2x}+1); v_exp_f32 computes 2^x, clamp-free, inf-safe.
    float e = __builtin_amdgcn_exp2f(x * 2.885390081777927f);
    return fmaf(-2.f, __builtin_amdgcn_rcpf(e + 1.f), 1.f);
}

__device__ inline void gld_lds16(const void* g, void* l) {
    __builtin_amdgcn_global_load_lds(
        (const __attribute__((address_space(1))) void*)g,
        (__attribute__((address_space(3))) void*)l, 16, 0, 0);
}

// hs element (row, col): chunk c = col/8, phys = (c&~7)|((c^(row&7))&7),
// offset row*512 + phys*8 + col%8.
__device__ inline int hs_off(int row, int col) {
    int c = col >> 3;
    int phys = (c & ~7) | ((c ^ (row & 7)) & 7);
    return row * 512 + phys * 8 + (col & 7);
}

// ---------------- combined prep (obs cast, 7 weight transposes, actions, nbias) ----------------
__global__ __launch_bounds__(256) void prep_kernel(
    const float* __restrict__ obs, const int* __restrict__ category,
    const float* __restrict__ qw0, const float* __restrict__ qw1,
    const float* __restrict__ qw2, const float* __restrict__ qw3,
    const float* __restrict__ vw0, const float* __restrict__ vw1,
    const float* __restrict__ vw2,
    __hip_bfloat16* __restrict__ obs_bf,
    __hip_bfloat16* __restrict__ w0t, __hip_bfloat16* __restrict__ w1t,
    __hip_bfloat16* __restrict__ w2t, __hip_bfloat16* __restrict__ w3t,
    __hip_bfloat16* __restrict__ vw0t, __hip_bfloat16* __restrict__ vw1t,
    __hip_bfloat16* __restrict__ vw2t,
    float* __restrict__ acts, float* __restrict__ nbias)
{
    const int bid = blockIdx.x, tid = threadIdx.x;
    if (bid < 2048) {
        int i = bid * 256 + tid;
        obs_bf[i] = __float2bfloat16(obs[i]);
    } else if (bid < 2560) {   // (512,128) transposes
        const float* src = (bid < 2304) ? qw0 : vw0;
        __hip_bfloat16* dst = (bid < 2304) ? w0t : vw0t;
        int idx = ((bid - 2048) & 255) * 256 + tid;
        int n = idx >> 7, k = idx & 127;
        dst[idx] = __float2bfloat16(src[k * 512 + n]);
    } else if (bid < 7680) {   // (512,512) transposes
        int job = (bid - 2560) >> 10;            // 0..4
        const float* srcs[5] = {qw1, qw2, qw3, vw1, vw2};
        __hip_bfloat16* dsts[5] = {w1t, w2t, w3t, vw1t, vw2t};
        int idx = ((bid - 2560) & 1023) * 256 + tid;
        int n = idx >> 9, k = idx & 511;
        dsts[job][idx] = __float2bfloat16(srcs[job][k * 512 + n]);
    } else if (bid < 11776) {  // actions table, s-major: acts[(s*4096+b)*8+d]
        int t = (bid - 7680) * 256 + tid;
        int d = t & 7;
        int r = t >> 3;
        int b = r & 4095, s = r >> 12;
        int U = (s >> 3) + ((d < (s & 7)) ? 1 : 0);
        float a = 0.f;
        if (U > 0) {
            float w = 0.125f, cum = 0.f;
            for (int j = 0; j < U; ++j) {
                cum += (float)category[b * 32 + j * 8 + d] * w;
                if (j == U - 1) a = -1.f + cum + 0.5f * w;
                w *= 0.0625f;
            }
        }
        acts[t] = a;
    } else {                   // nbias = 0
        int i = (bid - 11776) * 256 + tid;
        nbias[i] = 0.f;
    }
}

// ---------------- dual-job GEMM (m97-style, used only for the small P dispatch) ----------------
// epi=0: fp32 raw; epi=1: bf16(tanh(acc+bias)); epi=2: bf16 raw.
__global__ __launch_bounds__(256) void gemm_dual(
    const __hip_bfloat16* __restrict__ A0, const __hip_bfloat16* __restrict__ B0,
    const float* __restrict__ bias0, void* __restrict__ C0, int K0, int epi0, int nb0,
    const __hip_bfloat16* __restrict__ A1, const __hip_bfloat16* __restrict__ B1,
    const float* __restrict__ bias1, void* __restrict__ C1, int K1, int epi1)
{
    __shared__ __hip_bfloat16 As[128 * 32];
    __shared__ __hip_bfloat16 Bs[128 * 32];

    const __hip_bfloat16 *A, *Bt;
    const float* bias;
    void* Cout;
    int K, epi, tb;
    if ((int)blockIdx.x < nb0) {
        A = A0; Bt = B0; bias = bias0; Cout = C0; K = K0; epi = epi0; tb = blockIdx.x;
    } else {
        A = A1; Bt = B1; bias = bias1; Cout = C1; K = K1; epi = epi1; tb = blockIdx.x - nb0;
    }
    const long m0 = (long)(tb >> 2) * 128;
    const int  n0 = (tb & 3) * 128;

    const int tid  = threadIdx.x;
    const int wave = tid >> 6, lane = tid & 63;
    const int quad = lane >> 4, t = lane & 15;
    const int wr = wave >> 1, wc = wave & 1;

    f32x4_t acc[4][4] = {};

    const int lrow  = lane >> 2;
    const int lkoff = (((lane & 3) + (lane >> 3)) & 3) * 8;

    const __hip_bfloat16* Ag0 = A  + (m0 + wave * 32 +      lrow) * (long)K + lkoff;
    const __hip_bfloat16* Ag1 = A  + (m0 + wave * 32 + 16 + lrow) * (long)K + lkoff;
    const __hip_bfloat16* Bg0 = Bt + (long)(n0 + wave * 32 +      lrow) * K + lkoff;
    const __hip_bfloat16* Bg1 = Bt + (long)(n0 + wave * 32 + 16 + lrow) * K + lkoff;
    __hip_bfloat16* AsB0 = &As[(wave * 32) * 32];
    __hip_bfloat16* AsB1 = &As[(wave * 32 + 16) * 32];
    __hip_bfloat16* BsB0 = &Bs[(wave * 32) * 32];
    __hip_bfloat16* BsB1 = &Bs[(wave * 32 + 16) * 32];

    const int slot = ((quad - (t >> 1)) & 3) * 8;

    for (int k0 = 0; k0 < K; k0 += 32) {
        gld_lds16(Ag0 + k0, AsB0);
        gld_lds16(Ag1 + k0, AsB1);
        gld_lds16(Bg0 + k0, BsB0);
        gld_lds16(Bg1 + k0, BsB1);
        __syncthreads();
        bf16x8_t af[4], bfr[4];
        #pragma unroll
        for (int i = 0; i < 4; ++i)
            af[i] = *(const bf16x8_t*)&As[(wr * 64 + i * 16 + t) * 32 + slot];
        #pragma unroll
        for (int j = 0; j < 4; ++j)
            bfr[j] = *(const bf16x8_t*)&Bs[(wc * 64 + j * 16 + t) * 32 + slot];
        #pragma unroll
        for (int i = 0; i < 4; ++i)
            #pragma unroll
            for (int j = 0; j < 4; ++j)
                acc[i][j] = __builtin_amdgcn_mfma_f32_16x16x32_bf16(af[i], bfr[j], acc[i][j], 0, 0, 0);
        __syncthreads();
    }

    #pragma unroll
    for (int i = 0; i < 4; ++i) {
        const long rbase = m0 + wr * 64 + i * 16 + quad * 4;
        #pragma unroll
        for (int j = 0; j < 4; ++j) {
            const int col = n0 + wc * 64 + j * 16 + t;
            #pragma unroll
            for (int r = 0; r < 4; ++r) {
                float v = acc[i][j][r];
                if (epi == 1) {
                    v = fast_tanh(v + bias[col]);
                    ((__hip_bfloat16*)Cout)[(rbase + r) * 512 + col] = __float2bfloat16(v);
                } else if (epi == 2) {
                    ((__hip_bfloat16*)Cout)[(rbase + r) * 512 + col] = __float2bfloat16(v);
                } else {
                    ((float*)Cout)[(rbase + r) * 512 + col] = v;
                }
            }
        }
    }
}

// ---------------- fused MLP layer: hs(64x512) = tanh(hs @ W^T + bias) ----------------
// 8 waves; wave w owns out-cols [w*64, w*64+64). D = W·hs (out x batch):
// A-frag = W rows (from global/L2), B-frag = hs rows (LDS). Thread's 4 acc regs
// = 4 consecutive out-cols of one batch row -> packed ds_write_b64.
__device__ inline void mfma_layer(
    __hip_bfloat16* hs, const __hip_bfloat16* __restrict__ W,
    const float* __restrict__ bias, int w, int lane)
{
    const int quad = lane >> 4, t = lane & 15;
    const int n0w = w * 64;
    f32x4_t acc[4][4] = {};   // [rt = batch tile][j = out tile]
    #pragma unroll 2
    for (int kc = 0; kc < 16; ++kc) {
        bf16x8_t a[4];
        const int craw = kc * 4 + quad;
        const int phys = (craw & ~7) | ((craw ^ (t & 7)) & 7);
        #pragma unroll
        for (int rt = 0; rt < 4; ++rt)
            a[rt] = *(const bf16x8_t*)&hs[(rt * 16 + t) * 512 + phys * 8];
        #pragma unroll
        for (int j = 0; j < 4; ++j) {
            bf16x8_t wq = *(const bf16x8_t*)&W[(size_t)(n0w + j * 16 + t) * 512 + kc * 32 + quad * 8];
            #pragma unroll
            for (int rt = 0; rt < 4; ++rt)
                acc[rt][j] = __builtin_amdgcn_mfma_f32_16x16x32_bf16(wq, a[rt], acc[rt][j], 0, 0, 0);
        }
    }
    __syncthreads();   // all reads of hs complete
    #pragma unroll
    for (int j = 0; j < 4; ++j) {
        const int oc0 = n0w + j * 16 + quad * 4;     // 4 consecutive out cols
        const float4 bl = *(const float4*)&bias[oc0];
        const int cbase = oc0 >> 3;                  // logical chunk (8-aligned part)
        const int sub = (quad & 1) * 4;              // offset within chunk
        #pragma unroll
        for (int rt = 0; rt < 4; ++rt) {
            const int row = rt * 16 + t;
            union { __hip_bfloat16 b[4]; uint2 v; } o;
            o.b[0] = __float2bfloat16(fast_tanh(acc[rt][j][0] + bl.x));
            o.b[1] = __float2bfloat16(fast_tanh(acc[rt][j][1] + bl.y));
            o.b[2] = __float2bfloat16(fast_tanh(acc[rt][j][2] + bl.z));
            o.b[3] = __float2bfloat16(fast_tanh(acc[rt][j][3] + bl.w));
            const int phys = (cbase & ~7) | ((cbase ^ (row & 7)) & 7);
            *(uint2*)&hs[row * 512 + phys * 8 + sub] = o.v;
        }
    }
    __syncthreads();   // hs now holds the layer output
}

// ---------------- fused MLP kernel: q-blocks [0,2048), v-blocks [2048,2112) ----------------
__global__ __launch_bounds__(512, 4) void fused_kernel(
    const __hip_bfloat16* __restrict__ p_bf,   // (4096,512) = obs@W0a, raw bf16
    const __hip_bfloat16* __restrict__ pv_bf,  // (4096,512) = obs@vW0, raw bf16
    const float* __restrict__ acts,            // (131072,8) s-major
    const float* __restrict__ qw0, const float* __restrict__ qb0,
    const __hip_bfloat16* __restrict__ w1t, const float* __restrict__ qb1,
    const __hip_bfloat16* __restrict__ w2t, const float* __restrict__ qb2,
    const __hip_bfloat16* __restrict__ w3t, const float* __restrict__ qb3,
    float* __restrict__ advout,
    const float* __restrict__ vb0,
    const __hip_bfloat16* __restrict__ vw1t, const float* __restrict__ vb1,
    const __hip_bfloat16* __restrict__ vw2t, const float* __restrict__ vb2,
    const float* __restrict__ vw3, const float* __restrict__ vb3,
    float* __restrict__ vout)
{
    __shared__ __hip_bfloat16 hs[64 * 512];   // 64 KB
    const int bid = blockIdx.x;
    const int tid = threadIdx.x;
    const int w = tid >> 6, lane = tid & 63;
    const int quad = lane >> 4, t = lane & 15;
    const bool is_q = bid < 2048;
    const int s  = is_q ? (bid >> 6) : 0;
    const int mb = is_q ? (bid & 63) : (bid - 2048);

    // ---- phase 0: layer-0 activations into hs (pure VALU); wave w does rows w*8..w*8+8 ----
    {
        const int col0 = lane * 8;
        float bb[8];
        {
            const float* bsrc = is_q ? qb0 : vb0;
            float4 b0 = *(const float4*)&bsrc[col0];
            float4 b1 = *(const float4*)&bsrc[col0 + 4];
            bb[0] = b0.x; bb[1] = b0.y; bb[2] = b0.z; bb[3] = b0.w;
            bb[4] = b1.x; bb[5] = b1.y; bb[6] = b1.z; bb[7] = b1.w;
        }
        if (is_q) {
            float wr[8][8];
            #pragma unroll
            for (int d = 0; d < 8; ++d) {
                float4 u0 = *(const float4*)&qw0[(128 + d) * 512 + col0];
                float4 u1 = *(const float4*)&qw0[(128 + d) * 512 + col0 + 4];
                wr[d][0] = u0.x; wr[d][1] = u0.y; wr[d][2] = u0.z; wr[d][3] = u0.w;
                wr[d][4] = u1.x; wr[d][5] = u1.y; wr[d][6] = u1.z; wr[d][7] = u1.w;
            }
            for (int i = 0; i < 8; ++i) {
                const int row = w * 8 + i;
                const int b = mb * 64 + row;
                const long r = (long)s * 4096 + b;
                union { bf16x8_t vec; __hip_bfloat16 e[8]; } pu;
                pu.vec = *(const bf16x8_t*)&p_bf[(size_t)b * 512 + col0];
                float4 a0 = *(const float4*)&acts[r * 8];
                float4 a1 = *(const float4*)&acts[r * 8 + 4];
                float a[8] = {a0.x, a0.y, a0.z, a0.w, a1.x, a1.y, a1.z, a1.w};
                float v[8];
                #pragma unroll
                for (int cc = 0; cc < 8; ++cc) v[cc] = __bfloat162float(pu.e[cc]) + bb[cc];
                #pragma unroll
                for (int d = 0; d < 8; ++d)
                    #pragma unroll
                    for (int cc = 0; cc < 8; ++cc)
                        v[cc] = fmaf(a[d], wr[d][cc], v[cc]);
                union { bf16x8_t vec; __hip_bfloat16 e[8]; } o;
                #pragma unroll
                for (int cc = 0; cc < 8; ++cc) o.e[cc] = __float2bfloat16(fast_tanh(v[cc]));
                const int phys = (lane & ~7) | ((lane ^ (row & 7)) & 7);
                *(bf16x8_t*)&hs[row * 512 + phys * 8] = o.vec;
            }
        } else {
            for (int i = 0; i < 8; ++i) {
                const int row = w * 8 + i;
                const int b = mb * 64 + row;
                union { bf16x8_t vec; __hip_bfloat16 e[8]; } pu;
                pu.vec = *(const bf16x8_t*)&pv_bf[(size_t)b * 512 + col0];
                union { bf16x8_t vec; __hip_bfloat16 e[8]; } o;
                #pragma unroll
                for (int cc = 0; cc < 8; ++cc)
                    o.e[cc] = __float2bfloat16(fast_tanh(__bfloat162float(pu.e[cc]) + bb[cc]));
                const int phys = (lane & ~7) | ((lane ^ (row & 7)) & 7);
                *(bf16x8_t*)&hs[row * 512 + phys * 8] = o.vec;
            }
        }
    }
    __syncthreads();

    // ---- layers 1 and 2 ----
    mfma_layer(hs, is_q ? w1t : vw1t, is_q ? qb1 : vb1, w, lane);
    mfma_layer(hs, is_q ? w2t : vw2t, is_q ? qb2 : vb2, w, lane);

    // ---- layer 3 ----
    if (is_q) {
        // diag slice: 64 rows x 16 cols; waves 0..3 each take a 16-row tile.
        if (w < 4) {
            f32x4_t acc = {};
            #pragma unroll 4
            for (int kc = 0; kc < 16; ++kc) {
                const int craw = kc * 4 + quad;
                const int phys = (craw & ~7) | ((craw ^ (t & 7)) & 7);
                bf16x8_t a = *(const bf16x8_t*)&hs[(w * 16 + t) * 512 + phys * 8];
                bf16x8_t bq = *(const bf16x8_t*)&w3t[(size_t)(s * 16 + t) * 512 + kc * 32 + quad * 8];
                acc = __builtin_amdgcn_mfma_f32_16x16x32_bf16(a, bq, acc, 0, 0, 0);
            }
            const float bias3 = qb3[s * 16 + t];
            #pragma unroll
            for (int rr = 0; rr < 4; ++rr) {
                const int row = w * 16 + quad * 4 + rr;
                const int b = mb * 64 + row;
                advout[(size_t)b * 512 + s * 16 + t] = acc[rr] + bias3;
            }
        }
    } else {
        // value head: row = tid>>3 (0..63), seg = tid&7 sums 64 elems
        const int row = tid >> 3, seg = tid & 7;
        float sum = 0.f;
        for (int k = seg * 64; k < seg * 64 + 64; ++k)
            sum += __bfloat162float(hs[hs_off(row, k)]) * vw3[k];
        sum += __shfl_xor(sum, 1);
        sum += __shfl_xor(sum, 2);
        sum += __shfl_xor(sum, 4);
        if (seg == 0) vout[mb * 64 + row] = sum + vb3[0];
    }
}

// ---------------- launch ----------------
extern "C" void kernel_launch(void* const* d_in, const int* in_sizes, int n_in,
                              void* d_out, int out_size, void* d_ws, size_t ws_size,
                              hipStream_t stream) {
    const float* obs      = (const float*)d_in[0];
    const int*   category = (const int*)d_in[1];
    const float* v_w0 = (const float*)d_in[2];
    const float* v_b0 = (const float*)d_in[3];
    const float* v_w1 = (const float*)d_in[4];
    const float* v_b1 = (const float*)d_in[5];
    const float* v_w2 = (const float*)d_in[6];
    const float* v_b2 = (const float*)d_in[7];
    const float* v_w3 = (const float*)d_in[8];
    const float* v_b3 = (const float*)d_in[9];
    const float* q_w0 = (const float*)d_in[10];
    const float* q_b0 = (const float*)d_in[11];
    const float* q_w1 = (const float*)d_in[12];
    const float* q_b1 = (const float*)d_in[13];
    const float* q_w2 = (const float*)d_in[14];
    const float* q_b2 = (const float*)d_in[15];
    const float* q_w3 = (const float*)d_in[16];
    const float* q_b3 = (const float*)d_in[17];

    char* ws = (char*)d_ws;
    __hip_bfloat16* obs_bf = (__hip_bfloat16*)(ws + 0);              // 1 MB
    __hip_bfloat16* w0t    = (__hip_bfloat16*)(ws + 1048576);        // (512,128)
    __hip_bfloat16* vw0t   = (__hip_bfloat16*)(ws + 1179648);        // (512,128)
    __hip_bfloat16* w1t    = (__hip_bfloat16*)(ws + 1310720);        // (512,512)
    __hip_bfloat16* w2t    = (__hip_bfloat16*)(ws + 1835008);
    __hip_bfloat16* w3t    = (__hip_bfloat16*)(ws + 2359296);
    __hip_bfloat16* vw1t   = (__hip_bfloat16*)(ws + 2883584);
    __hip_bfloat16* vw2t   = (__hip_bfloat16*)(ws + 3407872);
    float*          acts   = (float*)         (ws + 3932160);        // (131072,8) fp32, 4 MB
    __hip_bfloat16* p_bf   = (__hip_bfloat16*)(ws + 8126464);        // (4096,512) bf16
    __hip_bfloat16* pv_bf  = (__hip_bfloat16*)(ws + 12320768);       // (4096,512) bf16

    float* out       = (float*)d_out;
    float* out_value = out;
    float* out_adv   = out + 4096;
    float* out_nbias = out + 4096 + (size_t)B_SZ * 512;

    // 1) all prep in one dispatch (incl. nbias zero)
    prep_kernel<<<12288, 256, 0, stream>>>(
        obs, category, q_w0, q_w1, q_w2, q_w3, v_w0, v_w1, v_w2,
        obs_bf, w0t, w1t, w2t, w3t, vw0t, vw1t, vw2t, acts, out_nbias);

    // 2) P: p_bf = obs@W0a || pv_bf = obs@vW0 (both raw bf16)
    gemm_dual<<<256, 256, 0, stream>>>(
        obs_bf, w0t, nullptr, p_bf, 128, 2, 128,
        obs_bf, vw0t, nullptr, pv_bf, 128, 2);

    // 3) fused q+v MLP (2048 q-blocks + 64 v-blocks), 512 threads
    fused_kernel<<<2112, 512, 0, stream>>>(
        p_bf, pv_bf, acts, q_w0, q_b0, w1t, q_b1, w2t, q_b2, w3t, q_b3, out_adv,
        v_b0, vw1t, v_b1, vw2t, v_b2, v_w3, v_b3, out_value);
}

// Round 9
// 283.883 us; speedup vs baseline: 1.9739x; 1.4843x over previous
//
#include <hip/hip_runtime.h>
#include <hip/hip_bf16.h>

// Problem constants
#define B_SZ   4096
#define OBS_N  128
#define HID    512

// S-MAJOR q rows: r = s*4096 + b. Fused kernel: block = 64 rows (one s, 64 b's),
// 512 threads (8 waves), 3 hidden layers chained through a 64KB LDS buffer
// (XOR-swizzled chunks). Layers compute D = W·hs (out x batch).
// W1/W2/W3 (and v) are stored MFMA-TILED: [out_tile][kc][lane][8] so a wave's
// W-frag load is one contiguous 1KB transaction; W frags are register-prefetched
// one kc ahead (wc/wn) to hide L2 latency. 3 dispatches: prep | P | fused.

typedef __bf16 bf16x8_t __attribute__((ext_vector_type(8)));
typedef float  f32x4_t  __attribute__((ext_vector_type(4)));

__device__ inline float fast_tanh(float x) {
    // tanh(x) = 1 - 2/(e^{2x}+1); v_exp_f32 computes 2^x, clamp-free, inf-safe.
    float e = __builtin_amdgcn_exp2f(x * 2.885390081777927f);
    return fmaf(-2.f, __builtin_amdgcn_rcpf(e + 1.f), 1.f);
}

__device__ inline void gld_lds16(const void* g, void* l) {
    __builtin_amdgcn_global_load_lds(
        (const __attribute__((address_space(1))) void*)g,
        (__attribute__((address_space(3))) void*)l, 16, 0, 0);
}

// hs element (row, col): chunk c = col/8, phys = (c&~7)|((c^(row&7))&7),
// offset row*512 + phys*8 + col%8.
__device__ inline int hs_off(int row, int col) {
    int c = col >> 3;
    int phys = (c & ~7) | ((c ^ (row & 7)) & 7);
    return row * 512 + phys * 8 + (col & 7);
}

// ---------------- combined prep ----------------
// (512,512) weights go to MFMA-tiled layout: idx = ((tile*16+kc)*64+lane)*8+e
// holds src[k*512+n] with k = kc*32+(lane>>4)*8+e, n = tile*16+(lane&15).
__global__ __launch_bounds__(256) void prep_kernel(
    const float* __restrict__ obs, const int* __restrict__ category,
    const float* __restrict__ qw0, const float* __restrict__ qw1,
    const float* __restrict__ qw2, const float* __restrict__ qw3,
    const float* __restrict__ vw0, const float* __restrict__ vw1,
    const float* __restrict__ vw2,
    __hip_bfloat16* __restrict__ obs_bf,
    __hip_bfloat16* __restrict__ w0t, __hip_bfloat16* __restrict__ w1t,
    __hip_bfloat16* __restrict__ w2t, __hip_bfloat16* __restrict__ w3t,
    __hip_bfloat16* __restrict__ vw0t, __hip_bfloat16* __restrict__ vw1t,
    __hip_bfloat16* __restrict__ vw2t,
    float* __restrict__ acts, float* __restrict__ nbias)
{
    const int bid = blockIdx.x, tid = threadIdx.x;
    if (bid < 2048) {
        int i = bid * 256 + tid;
        obs_bf[i] = __float2bfloat16(obs[i]);
    } else if (bid < 2560) {   // (512,128) transposes (row-major, for gemm_dual)
        const float* src = (bid < 2304) ? qw0 : vw0;
        __hip_bfloat16* dst = (bid < 2304) ? w0t : vw0t;
        int idx = ((bid - 2048) & 255) * 256 + tid;
        int n = idx >> 7, k = idx & 127;
        dst[idx] = __float2bfloat16(src[k * 512 + n]);
    } else if (bid < 7680) {   // (512,512) -> MFMA-tiled
        int job = (bid - 2560) >> 10;            // 0..4
        const float* srcs[5] = {qw1, qw2, qw3, vw1, vw2};
        __hip_bfloat16* dsts[5] = {w1t, w2t, w3t, vw1t, vw2t};
        int idx = ((bid - 2560) & 1023) * 256 + tid;   // 0..262143
        int e    = idx & 7;
        int lane = (idx >> 3) & 63;
        int kc   = (idx >> 9) & 15;
        int tile = idx >> 13;
        int k = kc * 32 + (lane >> 4) * 8 + e;
        int n = tile * 16 + (lane & 15);
        dsts[job][idx] = __float2bfloat16(srcs[job][k * 512 + n]);
    } else if (bid < 11776) {  // actions table, s-major: acts[(s*4096+b)*8+d]
        int t = (bid - 7680) * 256 + tid;
        int d = t & 7;
        int r = t >> 3;
        int b = r & 4095, s = r >> 12;
        int U = (s >> 3) + ((d < (s & 7)) ? 1 : 0);
        float a = 0.f;
        if (U > 0) {
            float w = 0.125f, cum = 0.f;
            for (int j = 0; j < U; ++j) {
                cum += (float)category[b * 32 + j * 8 + d] * w;
                if (j == U - 1) a = -1.f + cum + 0.5f * w;
                w *= 0.0625f;
            }
        }
        acts[t] = a;
    } else {                   // nbias = 0
        int i = (bid - 11776) * 256 + tid;
        nbias[i] = 0.f;
    }
}

// ---------------- dual-job GEMM (m97-style, used only for the small P dispatch) ----------------
__global__ __launch_bounds__(256) void gemm_dual(
    const __hip_bfloat16* __restrict__ A0, const __hip_bfloat16* __restrict__ B0,
    const float* __restrict__ bias0, void* __restrict__ C0, int K0, int epi0, int nb0,
    const __hip_bfloat16* __restrict__ A1, const __hip_bfloat16* __restrict__ B1,
    const float* __restrict__ bias1, void* __restrict__ C1, int K1, int epi1)
{
    __shared__ __hip_bfloat16 As[128 * 32];
    __shared__ __hip_bfloat16 Bs[128 * 32];

    const __hip_bfloat16 *A, *Bt;
    const float* bias;
    void* Cout;
    int K, epi, tb;
    if ((int)blockIdx.x < nb0) {
        A = A0; Bt = B0; bias = bias0; Cout = C0; K = K0; epi = epi0; tb = blockIdx.x;
    } else {
        A = A1; Bt = B1; bias = bias1; Cout = C1; K = K1; epi = epi1; tb = blockIdx.x - nb0;
    }
    const long m0 = (long)(tb >> 2) * 128;
    const int  n0 = (tb & 3) * 128;

    const int tid  = threadIdx.x;
    const int wave = tid >> 6, lane = tid & 63;
    const int quad = lane >> 4, t = lane & 15;
    const int wr = wave >> 1, wc = wave & 1;

    f32x4_t acc[4][4] = {};

    const int lrow  = lane >> 2;
    const int lkoff = (((lane & 3) + (lane >> 3)) & 3) * 8;

    const __hip_bfloat16* Ag0 = A  + (m0 + wave * 32 +      lrow) * (long)K + lkoff;
    const __hip_bfloat16* Ag1 = A  + (m0 + wave * 32 + 16 + lrow) * (long)K + lkoff;
    const __hip_bfloat16* Bg0 = Bt + (long)(n0 + wave * 32 +      lrow) * K + lkoff;
    const __hip_bfloat16* Bg1 = Bt + (long)(n0 + wave * 32 + 16 + lrow) * K + lkoff;
    __hip_bfloat16* AsB0 = &As[(wave * 32) * 32];
    __hip_bfloat16* AsB1 = &As[(wave * 32 + 16) * 32];
    __hip_bfloat16* BsB0 = &Bs[(wave * 32) * 32];
    __hip_bfloat16* BsB1 = &Bs[(wave * 32 + 16) * 32];

    const int slot = ((quad - (t >> 1)) & 3) * 8;

    for (int k0 = 0; k0 < K; k0 += 32) {
        gld_lds16(Ag0 + k0, AsB0);
        gld_lds16(Ag1 + k0, AsB1);
        gld_lds16(Bg0 + k0, BsB0);
        gld_lds16(Bg1 + k0, BsB1);
        __syncthreads();
        bf16x8_t af[4], bfr[4];
        #pragma unroll
        for (int i = 0; i < 4; ++i)
            af[i] = *(const bf16x8_t*)&As[(wr * 64 + i * 16 + t) * 32 + slot];
        #pragma unroll
        for (int j = 0; j < 4; ++j)
            bfr[j] = *(const bf16x8_t*)&Bs[(wc * 64 + j * 16 + t) * 32 + slot];
        #pragma unroll
        for (int i = 0; i < 4; ++i)
            #pragma unroll
            for (int j = 0; j < 4; ++j)
                acc[i][j] = __builtin_amdgcn_mfma_f32_16x16x32_bf16(af[i], bfr[j], acc[i][j], 0, 0, 0);
        __syncthreads();
    }

    #pragma unroll
    for (int i = 0; i < 4; ++i) {
        const long rbase = m0 + wr * 64 + i * 16 + quad * 4;
        #pragma unroll
        for (int j = 0; j < 4; ++j) {
            const int col = n0 + wc * 64 + j * 16 + t;
            #pragma unroll
            for (int r = 0; r < 4; ++r) {
                float v = acc[i][j][r];
                if (epi == 1) {
                    v = fast_tanh(v + bias[col]);
                    ((__hip_bfloat16*)Cout)[(rbase + r) * 512 + col] = __float2bfloat16(v);
                } else if (epi == 2) {
                    ((__hip_bfloat16*)Cout)[(rbase + r) * 512 + col] = __float2bfloat16(v);
                } else {
                    ((float*)Cout)[(rbase + r) * 512 + col] = v;
                }
            }
        }
    }
}

// ---------------- fused MLP layer: hs(64x512) = tanh(hs @ W^T + bias) ----------------
// 8 waves; wave w owns out-cols [w*64, w*64+64) = out tiles w*4..w*4+3.
// Wt is MFMA-tiled: frag(tile, kc) at Wt + ((tile*16+kc)*64 + lane)*8 — one 1KB
// coalesced load per frag. W frags prefetched one kc ahead (wc/wn).
__device__ inline void mfma_layer(
    __hip_bfloat16* hs, const __hip_bfloat16* __restrict__ Wt,
    const float* __restrict__ bias, int w, int lane)
{
    const int quad = lane >> 4, t = lane & 15;
    const int n0w = w * 64;
    const __hip_bfloat16* Wl = Wt + ((size_t)(w * 4) * 16 * 64 + lane) * 8;
    // frag(j, kc) = Wl + (j*16 + kc)*512 elements
    f32x4_t acc[4][4] = {};   // [rt = batch tile][j = out tile]
    bf16x8_t wc[4], wn[4], ac[4];
    #pragma unroll
    for (int j = 0; j < 4; ++j)
        wc[j] = *(const bf16x8_t*)(Wl + (size_t)(j * 16) * 512);

    #pragma unroll 2
    for (int kc = 0; kc < 16; ++kc) {
        const int craw = kc * 4 + quad;
        const int phys = (craw & ~7) | ((craw ^ (t & 7)) & 7);
        #pragma unroll
        for (int rt = 0; rt < 4; ++rt)
            ac[rt] = *(const bf16x8_t*)&hs[(rt * 16 + t) * 512 + phys * 8];
        if (kc < 15) {
            #pragma unroll
            for (int j = 0; j < 4; ++j)
                wn[j] = *(const bf16x8_t*)(Wl + (size_t)(j * 16 + kc + 1) * 512);
        }
        #pragma unroll
        for (int j = 0; j < 4; ++j)
            #pragma unroll
            for (int rt = 0; rt < 4; ++rt)
                acc[rt][j] = __builtin_amdgcn_mfma_f32_16x16x32_bf16(wc[j], ac[rt], acc[rt][j], 0, 0, 0);
        #pragma unroll
        for (int j = 0; j < 4; ++j) wc[j] = wn[j];
    }
    __syncthreads();   // all reads of hs complete
    #pragma unroll
    for (int j = 0; j < 4; ++j) {
        const int oc0 = n0w + j * 16 + quad * 4;     // 4 consecutive out cols
        const float4 bl = *(const float4*)&bias[oc0];
        const int cbase = oc0 >> 3;
        const int sub = (quad & 1) * 4;
        #pragma unroll
        for (int rt = 0; rt < 4; ++rt) {
            const int row = rt * 16 + t;
            union { __hip_bfloat16 b[4]; uint2 v; } o;
            o.b[0] = __float2bfloat16(fast_tanh(acc[rt][j][0] + bl.x));
            o.b[1] = __float2bfloat16(fast_tanh(acc[rt][j][1] + bl.y));
            o.b[2] = __float2bfloat16(fast_tanh(acc[rt][j][2] + bl.z));
            o.b[3] = __float2bfloat16(fast_tanh(acc[rt][j][3] + bl.w));
            const int phys = (cbase & ~7) | ((cbase ^ (row & 7)) & 7);
            *(uint2*)&hs[row * 512 + phys * 8 + sub] = o.v;
        }
    }
    __syncthreads();   // hs now holds the layer output
}

// ---------------- fused MLP kernel: q-blocks [0,2048), v-blocks [2048,2112) ----------------
__global__ __launch_bounds__(512, 4) void fused_kernel(
    const __hip_bfloat16* __restrict__ p_bf,   // (4096,512) = obs@W0a, raw bf16
    const __hip_bfloat16* __restrict__ pv_bf,  // (4096,512) = obs@vW0, raw bf16
    const float* __restrict__ acts,            // (131072,8) s-major
    const float* __restrict__ qw0, const float* __restrict__ qb0,
    const __hip_bfloat16* __restrict__ w1t, const float* __restrict__ qb1,
    const __hip_bfloat16* __restrict__ w2t, const float* __restrict__ qb2,
    const __hip_bfloat16* __restrict__ w3t, const float* __restrict__ qb3,
    float* __restrict__ advout,
    const float* __restrict__ vb0,
    const __hip_bfloat16* __restrict__ vw1t, const float* __restrict__ vb1,
    const __hip_bfloat16* __restrict__ vw2t, const float* __restrict__ vb2,
    const float* __restrict__ vw3, const float* __restrict__ vb3,
    float* __restrict__ vout)
{
    __shared__ __hip_bfloat16 hs[64 * 512];   // 64 KB
    const int bid = blockIdx.x;
    const int tid = threadIdx.x;
    const int w = tid >> 6, lane = tid & 63;
    const int quad = lane >> 4, t = lane & 15;
    const bool is_q = bid < 2048;
    const int s  = is_q ? (bid >> 6) : 0;
    const int mb = is_q ? (bid & 63) : (bid - 2048);

    // ---- phase 0: layer-0 activations into hs (pure VALU); wave w does rows w*8..w*8+8 ----
    {
        const int col0 = lane * 8;
        float bb[8];
        {
            const float* bsrc = is_q ? qb0 : vb0;
            float4 b0 = *(const float4*)&bsrc[col0];
            float4 b1 = *(const float4*)&bsrc[col0 + 4];
            bb[0] = b0.x; bb[1] = b0.y; bb[2] = b0.z; bb[3] = b0.w;
            bb[4] = b1.x; bb[5] = b1.y; bb[6] = b1.z; bb[7] = b1.w;
        }
        if (is_q) {
            float wr[8][8];
            #pragma unroll
            for (int d = 0; d < 8; ++d) {
                float4 u0 = *(const float4*)&qw0[(128 + d) * 512 + col0];
                float4 u1 = *(const float4*)&qw0[(128 + d) * 512 + col0 + 4];
                wr[d][0] = u0.x; wr[d][1] = u0.y; wr[d][2] = u0.z; wr[d][3] = u0.w;
                wr[d][4] = u1.x; wr[d][5] = u1.y; wr[d][6] = u1.z; wr[d][7] = u1.w;
            }
            for (int i = 0; i < 8; ++i) {
                const int row = w * 8 + i;
                const int b = mb * 64 + row;
                const long r = (long)s * 4096 + b;
                union { bf16x8_t vec; __hip_bfloat16 e[8]; } pu;
                pu.vec = *(const bf16x8_t*)&p_bf[(size_t)b * 512 + col0];
                float4 a0 = *(const float4*)&acts[r * 8];
                float4 a1 = *(const float4*)&acts[r * 8 + 4];
                float a[8] = {a0.x, a0.y, a0.z, a0.w, a1.x, a1.y, a1.z, a1.w};
                float v[8];
                #pragma unroll
                for (int cc = 0; cc < 8; ++cc) v[cc] = __bfloat162float(pu.e[cc]) + bb[cc];
                #pragma unroll
                for (int d = 0; d < 8; ++d)
                    #pragma unroll
                    for (int cc = 0; cc < 8; ++cc)
                        v[cc] = fmaf(a[d], wr[d][cc], v[cc]);
                union { bf16x8_t vec; __hip_bfloat16 e[8]; } o;
                #pragma unroll
                for (int cc = 0; cc < 8; ++cc) o.e[cc] = __float2bfloat16(fast_tanh(v[cc]));
                const int phys = (lane & ~7) | ((lane ^ (row & 7)) & 7);
                *(bf16x8_t*)&hs[row * 512 + phys * 8] = o.vec;
            }
        } else {
            for (int i = 0; i < 8; ++i) {
                const int row = w * 8 + i;
                const int b = mb * 64 + row;
                union { bf16x8_t vec; __hip_bfloat16 e[8]; } pu;
                pu.vec = *(const bf16x8_t*)&pv_bf[(size_t)b * 512 + col0];
                union { bf16x8_t vec; __hip_bfloat16 e[8]; } o;
                #pragma unroll
                for (int cc = 0; cc < 8; ++cc)
                    o.e[cc] = __float2bfloat16(fast_tanh(__bfloat162float(pu.e[cc]) + bb[cc]));
                const int phys = (lane & ~7) | ((lane ^ (row & 7)) & 7);
                *(bf16x8_t*)&hs[row * 512 + phys * 8] = o.vec;
            }
        }
    }
    __syncthreads();

    // ---- layers 1 and 2 ----
    mfma_layer(hs, is_q ? w1t : vw1t, is_q ? qb1 : vb1, w, lane);
    mfma_layer(hs, is_q ? w2t : vw2t, is_q ? qb2 : vb2, w, lane);

    // ---- layer 3 ----
    if (is_q) {
        // diag slice: 64 rows x 16 cols; waves 0..3 each take a 16-row tile.
        if (w < 4) {
            const __hip_bfloat16* W3l = w3t + ((size_t)s * 16 * 64 + (size_t)lane) * 8;
            f32x4_t acc = {};
            #pragma unroll 4
            for (int kc = 0; kc < 16; ++kc) {
                const int craw = kc * 4 + quad;
                const int phys = (craw & ~7) | ((craw ^ (t & 7)) & 7);
                bf16x8_t a = *(const bf16x8_t*)&hs[(w * 16 + t) * 512 + phys * 8];
                bf16x8_t bq = *(const bf16x8_t*)(W3l + (size_t)kc * 512);
                acc = __builtin_amdgcn_mfma_f32_16x16x32_bf16(a, bq, acc, 0, 0, 0);
            }
            const float bias3 = qb3[s * 16 + t];
            #pragma unroll
            for (int rr = 0; rr < 4; ++rr) {
                const int row = w * 16 + quad * 4 + rr;
                const int b = mb * 64 + row;
                advout[(size_t)b * 512 + s * 16 + t] = acc[rr] + bias3;
            }
        }
    } else {
        // value head: row = tid>>3 (0..63), seg = tid&7 sums 64 elems
        const int row = tid >> 3, seg = tid & 7;
        float sum = 0.f;
        for (int k = seg * 64; k < seg * 64 + 64; ++k)
            sum += __bfloat162float(hs[hs_off(row, k)]) * vw3[k];
        sum += __shfl_xor(sum, 1);
        sum += __shfl_xor(sum, 2);
        sum += __shfl_xor(sum, 4);
        if (seg == 0) vout[mb * 64 + row] = sum + vb3[0];
    }
}

// ---------------- launch ----------------
extern "C" void kernel_launch(void* const* d_in, const int* in_sizes, int n_in,
                              void* d_out, int out_size, void* d_ws, size_t ws_size,
                              hipStream_t stream) {
    const float* obs      = (const float*)d_in[0];
    const int*   category = (const int*)d_in[1];
    const float* v_w0 = (const float*)d_in[2];
    const float* v_b0 = (const float*)d_in[3];
    const float* v_w1 = (const float*)d_in[4];
    const float* v_b1 = (const float*)d_in[5];
    const float* v_w2 = (const float*)d_in[6];
    const float* v_b2 = (const float*)d_in[7];
    const float* v_w3 = (const float*)d_in[8];
    const float* v_b3 = (const float*)d_in[9];
    const float* q_w0 = (const float*)d_in[10];
    const float* q_b0 = (const float*)d_in[11];
    const float* q_w1 = (const float*)d_in[12];
    const float* q_b1 = (const float*)d_in[13];
    const float* q_w2 = (const float*)d_in[14];
    const float* q_b2 = (const float*)d_in[15];
    const float* q_w3 = (const float*)d_in[16];
    const float* q_b3 = (const float*)d_in[17];

    char* ws = (char*)d_ws;
    __hip_bfloat16* obs_bf = (__hip_bfloat16*)(ws + 0);              // 1 MB
    __hip_bfloat16* w0t    = (__hip_bfloat16*)(ws + 1048576);        // (512,128) row-major
    __hip_bfloat16* vw0t   = (__hip_bfloat16*)(ws + 1179648);        // (512,128) row-major
    __hip_bfloat16* w1t    = (__hip_bfloat16*)(ws + 1310720);        // (512,512) tiled
    __hip_bfloat16* w2t    = (__hip_bfloat16*)(ws + 1835008);
    __hip_bfloat16* w3t    = (__hip_bfloat16*)(ws + 2359296);
    __hip_bfloat16* vw1t   = (__hip_bfloat16*)(ws + 2883584);
    __hip_bfloat16* vw2t   = (__hip_bfloat16*)(ws + 3407872);
    float*          acts   = (float*)         (ws + 3932160);        // (131072,8) fp32, 4 MB
    __hip_bfloat16* p_bf   = (__hip_bfloat16*)(ws + 8126464);        // (4096,512) bf16
    __hip_bfloat16* pv_bf  = (__hip_bfloat16*)(ws + 12320768);       // (4096,512) bf16

    float* out       = (float*)d_out;
    float* out_value = out;
    float* out_adv   = out + 4096;
    float* out_nbias = out + 4096 + (size_t)B_SZ * 512;

    // 1) all prep in one dispatch (incl. nbias zero)
    prep_kernel<<<12288, 256, 0, stream>>>(
        obs, category, q_w0, q_w1, q_w2, q_w3, v_w0, v_w1, v_w2,
        obs_bf, w0t, w1t, w2t, w3t, vw0t, vw1t, vw2t, acts, out_nbias);

    // 2) P: p_bf = obs@W0a || pv_bf = obs@vW0 (both raw bf16)
    gemm_dual<<<256, 256, 0, stream>>>(
        obs_bf, w0t, nullptr, p_bf, 128, 2, 128,
        obs_bf, vw0t, nullptr, pv_bf, 128, 2);

    // 3) fused q+v MLP (2048 q-blocks + 64 v-blocks), 512 threads
    fused_kernel<<<2112, 512, 0, stream>>>(
        p_bf, pv_bf, acts, q_w0, q_b0, w1t, q_b1, w2t, q_b2, w3t, q_b3, out_adv,
        v_b0, vw1t, v_b1, vw2t, v_b2, v_w3, v_b3, out_value);
}

// Round 10
// 278.496 us; speedup vs baseline: 2.0121x; 1.0193x over previous
//
#include <hip/hip_runtime.h>
#include <hip/hip_bf16.h>

// Problem constants
#define B_SZ   4096
#define OBS_N  128
#define HID    512

// S-MAJOR q rows: r = s*4096 + b. Fused kernel: block = 64 rows (one s, 64 b's),
// 512 threads (8 waves), 3 hidden layers chained through a 64KB LDS buffer
// (XOR-swizzled chunks). Layers compute D = W·hs (out x batch).
// W1/W2/W3 (and v) MFMA-TILED: frag(tile,kc) = one 1KB coalesced load, register-
// prefetched one kc ahead. Phase 0 is ALSO MFMA: acc init from fp32 p, K=32 pass
// with augmented W0 (8 action rows + bias row), acts as bf16x8 B-frags.
// 3 dispatches: prep | P | fused.

typedef __bf16 bf16x8_t __attribute__((ext_vector_type(8)));
typedef float  f32x4_t  __attribute__((ext_vector_type(4)));

__device__ inline float fast_tanh(float x) {
    // tanh(x) = 1 - 2/(e^{2x}+1); v_exp_f32 computes 2^x, clamp-free, inf-safe.
    float e = __builtin_amdgcn_exp2f(x * 2.885390081777927f);
    return fmaf(-2.f, __builtin_amdgcn_rcpf(e + 1.f), 1.f);
}

__device__ inline void gld_lds16(const void* g, void* l) {
    __builtin_amdgcn_global_load_lds(
        (const __attribute__((address_space(1))) void*)g,
        (__attribute__((address_space(3))) void*)l, 16, 0, 0);
}

// hs element (row, col): chunk c = col/8, phys = (c&~7)|((c^(row&7))&7),
// offset row*512 + phys*8 + col%8.
__device__ inline int hs_off(int row, int col) {
    int c = col >> 3;
    int phys = (c & ~7) | ((c ^ (row & 7)) & 7);
    return row * 512 + phys * 8 + (col & 7);
}

// ---------------- combined prep ----------------
// (512,512) weights -> MFMA-tiled: idx=((tile*16+kc)*64+lane)*8+e holds
// src[k*512+n], k = kc*32+(lane>>4)*8+e, n = tile*16+(lane&15).
// W0aug (33x512 logical, K=32 padded) tiled: idx=(tile*64+lane)*8+e holds
// W0aug[k][n], k=(lane>>4)*8+e, n=tile*16+(lane&15);
// W0aug[k][n] = k<8 ? qw0[(128+k)*512+n] : (k==8 ? qb0[n] : 0).
__global__ __launch_bounds__(256) void prep_kernel(
    const float* __restrict__ obs, const int* __restrict__ category,
    const float* __restrict__ qw0, const float* __restrict__ qb0,
    const float* __restrict__ qw1, const float* __restrict__ qw2,
    const float* __restrict__ qw3,
    const float* __restrict__ vw0, const float* __restrict__ vb0,
    const float* __restrict__ vw1, const float* __restrict__ vw2,
    __hip_bfloat16* __restrict__ obs_bf,
    __hip_bfloat16* __restrict__ w0t, __hip_bfloat16* __restrict__ w1t,
    __hip_bfloat16* __restrict__ w2t, __hip_bfloat16* __restrict__ w3t,
    __hip_bfloat16* __restrict__ vw0t, __hip_bfloat16* __restrict__ vw1t,
    __hip_bfloat16* __restrict__ vw2t,
    __hip_bfloat16* __restrict__ w0aug, __hip_bfloat16* __restrict__ vw0aug,
    __hip_bfloat16* __restrict__ acts_bf, float* __restrict__ nbias)
{
    const int bid = blockIdx.x, tid = threadIdx.x;
    if (bid < 2048) {
        int i = bid * 256 + tid;
        obs_bf[i] = __float2bfloat16(obs[i]);
    } else if (bid < 2560) {   // (512,128) transposes (row-major, for gemm_dual)
        const float* src = (bid < 2304) ? qw0 : vw0;
        __hip_bfloat16* dst = (bid < 2304) ? w0t : vw0t;
        int idx = ((bid - 2048) & 255) * 256 + tid;
        int n = idx >> 7, k = idx & 127;
        dst[idx] = __float2bfloat16(src[k * 512 + n]);
    } else if (bid < 7680) {   // (512,512) -> MFMA-tiled
        int job = (bid - 2560) >> 10;            // 0..4
        const float* srcs[5] = {qw1, qw2, qw3, vw1, vw2};
        __hip_bfloat16* dsts[5] = {w1t, w2t, w3t, vw1t, vw2t};
        int idx = ((bid - 2560) & 1023) * 256 + tid;   // 0..262143
        int e    = idx & 7;
        int lane = (idx >> 3) & 63;
        int kc   = (idx >> 9) & 15;
        int tile = idx >> 13;
        int k = kc * 32 + (lane >> 4) * 8 + e;
        int n = tile * 16 + (lane & 15);
        dsts[job][idx] = __float2bfloat16(srcs[job][k * 512 + n]);
    } else if (bid < 11776) {  // acts_bf table, s-major bf16: acts_bf[(s*4096+b)*8+d]
        int t = (bid - 7680) * 256 + tid;
        int d = t & 7;
        int r = t >> 3;
        int b = r & 4095, s = r >> 12;
        int U = (s >> 3) + ((d < (s & 7)) ? 1 : 0);
        float a = 0.f;
        if (U > 0) {
            float w = 0.125f, cum = 0.f;
            for (int j = 0; j < U; ++j) {
                cum += (float)category[b * 32 + j * 8 + d] * w;
                if (j == U - 1) a = -1.f + cum + 0.5f * w;
                w *= 0.0625f;
            }
        }
        acts_bf[t] = __float2bfloat16(a);
    } else if (bid < 11904) {  // w0aug + vw0aug (64 blocks each)
        int sub = bid - 11776;
        bool isv = sub >= 64;
        int idx = (sub & 63) * 256 + tid;   // 0..16383
        int e    = idx & 7;
        int lane = (idx >> 3) & 63;
        int tile = idx >> 9;
        int k = (lane >> 4) * 8 + e;
        int n = tile * 16 + (lane & 15);
        float v = 0.f;
        if (!isv) {
            if (k < 8) v = qw0[(128 + k) * 512 + n];
            else if (k == 8) v = qb0[n];
            w0aug[idx] = __float2bfloat16(v);
        } else {
            if (k == 8) v = vb0[n];
            vw0aug[idx] = __float2bfloat16(v);
        }
    } else {                   // nbias = 0
        int i = (bid - 11904) * 256 + tid;
        nbias[i] = 0.f;
    }
}

// ---------------- dual-job GEMM (m97-style, used only for the small P dispatch) ----------------
__global__ __launch_bounds__(256) void gemm_dual(
    const __hip_bfloat16* __restrict__ A0, const __hip_bfloat16* __restrict__ B0,
    const float* __restrict__ bias0, void* __restrict__ C0, int K0, int epi0, int nb0,
    const __hip_bfloat16* __restrict__ A1, const __hip_bfloat16* __restrict__ B1,
    const float* __restrict__ bias1, void* __restrict__ C1, int K1, int epi1)
{
    __shared__ __hip_bfloat16 As[128 * 32];
    __shared__ __hip_bfloat16 Bs[128 * 32];

    const __hip_bfloat16 *A, *Bt;
    const float* bias;
    void* Cout;
    int K, epi, tb;
    if ((int)blockIdx.x < nb0) {
        A = A0; Bt = B0; bias = bias0; Cout = C0; K = K0; epi = epi0; tb = blockIdx.x;
    } else {
        A = A1; Bt = B1; bias = bias1; Cout = C1; K = K1; epi = epi1; tb = blockIdx.x - nb0;
    }
    const long m0 = (long)(tb >> 2) * 128;
    const int  n0 = (tb & 3) * 128;

    const int tid  = threadIdx.x;
    const int wave = tid >> 6, lane = tid & 63;
    const int quad = lane >> 4, t = lane & 15;
    const int wr = wave >> 1, wc = wave & 1;

    f32x4_t acc[4][4] = {};

    const int lrow  = lane >> 2;
    const int lkoff = (((lane & 3) + (lane >> 3)) & 3) * 8;

    const __hip_bfloat16* Ag0 = A  + (m0 + wave * 32 +      lrow) * (long)K + lkoff;
    const __hip_bfloat16* Ag1 = A  + (m0 + wave * 32 + 16 + lrow) * (long)K + lkoff;
    const __hip_bfloat16* Bg0 = Bt + (long)(n0 + wave * 32 +      lrow) * K + lkoff;
    const __hip_bfloat16* Bg1 = Bt + (long)(n0 + wave * 32 + 16 + lrow) * K + lkoff;
    __hip_bfloat16* AsB0 = &As[(wave * 32) * 32];
    __hip_bfloat16* AsB1 = &As[(wave * 32 + 16) * 32];
    __hip_bfloat16* BsB0 = &Bs[(wave * 32) * 32];
    __hip_bfloat16* BsB1 = &Bs[(wave * 32 + 16) * 32];

    const int slot = ((quad - (t >> 1)) & 3) * 8;

    for (int k0 = 0; k0 < K; k0 += 32) {
        gld_lds16(Ag0 + k0, AsB0);
        gld_lds16(Ag1 + k0, AsB1);
        gld_lds16(Bg0 + k0, BsB0);
        gld_lds16(Bg1 + k0, BsB1);
        __syncthreads();
        bf16x8_t af[4], bfr[4];
        #pragma unroll
        for (int i = 0; i < 4; ++i)
            af[i] = *(const bf16x8_t*)&As[(wr * 64 + i * 16 + t) * 32 + slot];
        #pragma unroll
        for (int j = 0; j < 4; ++j)
            bfr[j] = *(const bf16x8_t*)&Bs[(wc * 64 + j * 16 + t) * 32 + slot];
        #pragma unroll
        for (int i = 0; i < 4; ++i)
            #pragma unroll
            for (int j = 0; j < 4; ++j)
                acc[i][j] = __builtin_amdgcn_mfma_f32_16x16x32_bf16(af[i], bfr[j], acc[i][j], 0, 0, 0);
        __syncthreads();
    }

    #pragma unroll
    for (int i = 0; i < 4; ++i) {
        const long rbase = m0 + wr * 64 + i * 16 + quad * 4;
        #pragma unroll
        for (int j = 0; j < 4; ++j) {
            const int col = n0 + wc * 64 + j * 16 + t;
            #pragma unroll
            for (int r = 0; r < 4; ++r) {
                float v = acc[i][j][r];
                if (epi == 1) {
                    v = fast_tanh(v + bias[col]);
                    ((__hip_bfloat16*)Cout)[(rbase + r) * 512 + col] = __float2bfloat16(v);
                } else if (epi == 2) {
                    ((__hip_bfloat16*)Cout)[(rbase + r) * 512 + col] = __float2bfloat16(v);
                } else {
                    ((float*)Cout)[(rbase + r) * 512 + col] = v;
                }
            }
        }
    }
}

// ---------------- epilogue: tanh(acc) -> hs (XOR-swizzled), optional bias ----------------
__device__ inline void epi_store(
    __hip_bfloat16* hs, f32x4_t acc[4][4], const float* bias,
    int n0w, int quad, int t)
{
    #pragma unroll
    for (int j = 0; j < 4; ++j) {
        const int oc0 = n0w + j * 16 + quad * 4;     // 4 consecutive out cols
        float4 bl = {0.f, 0.f, 0.f, 0.f};
        if (bias) bl = *(const float4*)&bias[oc0];
        const int cbase = oc0 >> 3;
        const int sub = (quad & 1) * 4;
        #pragma unroll
        for (int rt = 0; rt < 4; ++rt) {
            const int row = rt * 16 + t;
            union { __hip_bfloat16 b[4]; uint2 v; } o;
            o.b[0] = __float2bfloat16(fast_tanh(acc[rt][j][0] + bl.x));
            o.b[1] = __float2bfloat16(fast_tanh(acc[rt][j][1] + bl.y));
            o.b[2] = __float2bfloat16(fast_tanh(acc[rt][j][2] + bl.z));
            o.b[3] = __float2bfloat16(fast_tanh(acc[rt][j][3] + bl.w));
            const int phys = (cbase & ~7) | ((cbase ^ (row & 7)) & 7);
            *(uint2*)&hs[row * 512 + phys * 8 + sub] = o.v;
        }
    }
}

// ---------------- fused MLP layer: hs(64x512) = tanh(hs @ W^T + bias) ----------------
__device__ inline void mfma_layer(
    __hip_bfloat16* hs, const __hip_bfloat16* __restrict__ Wt,
    const float* __restrict__ bias, int w, int lane)
{
    const int quad = lane >> 4, t = lane & 15;
    const int n0w = w * 64;
    const __hip_bfloat16* Wl = Wt + ((size_t)(w * 4) * 16 * 64 + lane) * 8;
    f32x4_t acc[4][4] = {};   // [rt = batch tile][j = out tile]
    bf16x8_t wc[4], wn[4], ac[4];
    #pragma unroll
    for (int j = 0; j < 4; ++j)
        wc[j] = *(const bf16x8_t*)(Wl + (size_t)(j * 16) * 512);

    #pragma unroll 2
    for (int kc = 0; kc < 16; ++kc) {
        const int craw = kc * 4 + quad;
        const int phys = (craw & ~7) | ((craw ^ (t & 7)) & 7);
        #pragma unroll
        for (int rt = 0; rt < 4; ++rt)
            ac[rt] = *(const bf16x8_t*)&hs[(rt * 16 + t) * 512 + phys * 8];
        if (kc < 15) {
            #pragma unroll
            for (int j = 0; j < 4; ++j)
                wn[j] = *(const bf16x8_t*)(Wl + (size_t)(j * 16 + kc + 1) * 512);
        }
        #pragma unroll
        for (int j = 0; j < 4; ++j)
            #pragma unroll
            for (int rt = 0; rt < 4; ++rt)
                acc[rt][j] = __builtin_amdgcn_mfma_f32_16x16x32_bf16(wc[j], ac[rt], acc[rt][j], 0, 0, 0);
        #pragma unroll
        for (int j = 0; j < 4; ++j) wc[j] = wn[j];
    }
    __syncthreads();   // all reads of hs complete
    epi_store(hs, acc, bias, n0w, quad, t);
    __syncthreads();   // hs now holds the layer output
}

// ---------------- fused MLP kernel: q-blocks [0,2048), v-blocks [2048,2112) ----------------
__global__ __launch_bounds__(512, 4) void fused_kernel(
    const float* __restrict__ p,               // (4096,512) fp32 = obs@W0a (no bias)
    const float* __restrict__ pv,              // (4096,512) fp32 = obs@vW0 (no bias)
    const __hip_bfloat16* __restrict__ acts_bf,// (131072,8) bf16 s-major
    const __hip_bfloat16* __restrict__ w0aug,  // tiled aug (32 tiles)
    const __hip_bfloat16* __restrict__ vw0aug,
    const __hip_bfloat16* __restrict__ w1t, const float* __restrict__ qb1,
    const __hip_bfloat16* __restrict__ w2t, const float* __restrict__ qb2,
    const __hip_bfloat16* __restrict__ w3t, const float* __restrict__ qb3,
    float* __restrict__ advout,
    const __hip_bfloat16* __restrict__ vw1t, const float* __restrict__ vb1,
    const __hip_bfloat16* __restrict__ vw2t, const float* __restrict__ vb2,
    const float* __restrict__ vw3, const float* __restrict__ vb3,
    float* __restrict__ vout)
{
    __shared__ __hip_bfloat16 hs[64 * 512];   // 64 KB
    const int bid = blockIdx.x;
    const int tid = threadIdx.x;
    const int w = tid >> 6, lane = tid & 63;
    const int quad = lane >> 4, t = lane & 15;
    const bool is_q = bid < 2048;
    const int s  = is_q ? (bid >> 6) : 0;
    const int mb = is_q ? (bid & 63) : (bid - 2048);
    const int n0w = w * 64;

    // ---- phase 0 as MFMA: D = W0aug·[acts;1] + p ----
    {
        const float* P = is_q ? p : pv;
        const __hip_bfloat16* W0 = is_q ? w0aug : vw0aug;
        f32x4_t acc[4][4];
        // acc init from fp32 p: acc[rt][j][rr] = P[br][oc], br = mb*64+rt*16+t,
        // oc = n0w + j*16 + quad*4 + rr
        #pragma unroll
        for (int rt = 0; rt < 4; ++rt) {
            const float* Prow = &P[(size_t)(mb * 64 + rt * 16 + t) * 512 + n0w + quad * 4];
            #pragma unroll
            for (int j = 0; j < 4; ++j)
                acc[rt][j] = *(const f32x4_t*)(Prow + j * 16);
        }
        // B-frags: quad0 = acts (q only), quad1 = e0 1.0, else 0
        bf16x8_t bfrag[4];
        #pragma unroll
        for (int rt = 0; rt < 4; ++rt) {
            union { bf16x8_t vec; unsigned short u[8]; } bu;
            #pragma unroll
            for (int i = 0; i < 8; ++i) bu.u[i] = 0;
            if (quad == 1) bu.u[0] = 0x3F80;   // bf16 1.0
            if (is_q && quad == 0) {
                const long r = (long)s * 4096 + mb * 64 + rt * 16 + t;
                bu.vec = *(const bf16x8_t*)&acts_bf[r * 8];
            }
            bfrag[rt] = bu.vec;
        }
        // A-frags (one "kc"): tile w*4+j at W0 + ((w*4+j)*64+lane)*8
        bf16x8_t wq[4];
        #pragma unroll
        for (int j = 0; j < 4; ++j)
            wq[j] = *(const bf16x8_t*)(W0 + ((size_t)(w * 4 + j) * 64 + lane) * 8);
        #pragma unroll
        for (int j = 0; j < 4; ++j)
            #pragma unroll
            for (int rt = 0; rt < 4; ++rt)
                acc[rt][j] = __builtin_amdgcn_mfma_f32_16x16x32_bf16(wq[j], bfrag[rt], acc[rt][j], 0, 0, 0);
        epi_store(hs, acc, nullptr, n0w, quad, t);
    }
    __syncthreads();

    // ---- layers 1 and 2 ----
    mfma_layer(hs, is_q ? w1t : vw1t, is_q ? qb1 : vb1, w, lane);
    mfma_layer(hs, is_q ? w2t : vw2t, is_q ? qb2 : vb2, w, lane);

    // ---- layer 3 ----
    if (is_q) {
        // diag slice: 64 rows x 16 cols; waves 0..3 each take a 16-row tile.
        if (w < 4) {
            const __hip_bfloat16* W3l = w3t + ((size_t)s * 16 * 64 + (size_t)lane) * 8;
            f32x4_t acc = {};
            #pragma unroll 4
            for (int kc = 0; kc < 16; ++kc) {
                const int craw = kc * 4 + quad;
                const int phys = (craw & ~7) | ((craw ^ (t & 7)) & 7);
                bf16x8_t a = *(const bf16x8_t*)&hs[(w * 16 + t) * 512 + phys * 8];
                bf16x8_t bq = *(const bf16x8_t*)(W3l + (size_t)kc * 512);
                acc = __builtin_amdgcn_mfma_f32_16x16x32_bf16(a, bq, acc, 0, 0, 0);
            }
            const float bias3 = qb3[s * 16 + t];
            #pragma unroll
            for (int rr = 0; rr < 4; ++rr) {
                const int row = w * 16 + quad * 4 + rr;
                const int b = mb * 64 + row;
                advout[(size_t)b * 512 + s * 16 + t] = acc[rr] + bias3;
            }
        }
    } else {
        // value head: row = tid>>3 (0..63), seg = tid&7 sums 64 elems
        const int row = tid >> 3, seg = tid & 7;
        float sum = 0.f;
        for (int k = seg * 64; k < seg * 64 + 64; ++k)
            sum += __bfloat162float(hs[hs_off(row, k)]) * vw3[k];
        sum += __shfl_xor(sum, 1);
        sum += __shfl_xor(sum, 2);
        sum += __shfl_xor(sum, 4);
        if (seg == 0) vout[mb * 64 + row] = sum + vb3[0];
    }
}

// ---------------- launch ----------------
extern "C" void kernel_launch(void* const* d_in, const int* in_sizes, int n_in,
                              void* d_out, int out_size, void* d_ws, size_t ws_size,
                              hipStream_t stream) {
    const float* obs      = (const float*)d_in[0];
    const int*   category = (const int*)d_in[1];
    const float* v_w0 = (const float*)d_in[2];
    const float* v_b0 = (const float*)d_in[3];
    const float* v_w1 = (const float*)d_in[4];
    const float* v_b1 = (const float*)d_in[5];
    const float* v_w2 = (const float*)d_in[6];
    const float* v_b2 = (const float*)d_in[7];
    const float* v_w3 = (const float*)d_in[8];
    const float* v_b3 = (const float*)d_in[9];
    const float* q_w0 = (const float*)d_in[10];
    const float* q_b0 = (const float*)d_in[11];
    const float* q_w1 = (const float*)d_in[12];
    const float* q_b1 = (const float*)d_in[13];
    const float* q_w2 = (const float*)d_in[14];
    const float* q_b2 = (const float*)d_in[15];
    const float* q_w3 = (const float*)d_in[16];
    const float* q_b3 = (const float*)d_in[17];

    char* ws = (char*)d_ws;
    __hip_bfloat16* obs_bf = (__hip_bfloat16*)(ws + 0);              // 1 MB
    __hip_bfloat16* w0t    = (__hip_bfloat16*)(ws + 1048576);        // (512,128) row-major
    __hip_bfloat16* vw0t   = (__hip_bfloat16*)(ws + 1179648);        // (512,128) row-major
    __hip_bfloat16* w1t    = (__hip_bfloat16*)(ws + 1310720);        // (512,512) tiled
    __hip_bfloat16* w2t    = (__hip_bfloat16*)(ws + 1835008);
    __hip_bfloat16* w3t    = (__hip_bfloat16*)(ws + 2359296);
    __hip_bfloat16* vw1t   = (__hip_bfloat16*)(ws + 2883584);
    __hip_bfloat16* vw2t   = (__hip_bfloat16*)(ws + 3407872);
    __hip_bfloat16* w0aug  = (__hip_bfloat16*)(ws + 3932160);        // 32 KB
    __hip_bfloat16* vw0aug = (__hip_bfloat16*)(ws + 3964928);        // 32 KB
    __hip_bfloat16* acts_bf= (__hip_bfloat16*)(ws + 3997696);        // (131072,8) bf16, 2 MB
    float*          p      = (float*)         (ws + 6094848);        // (4096,512) fp32, 8 MB
    float*          pv     = (float*)         (ws + 14483456);       // (4096,512) fp32, 8 MB

    float* out       = (float*)d_out;
    float* out_value = out;
    float* out_adv   = out + 4096;
    float* out_nbias = out + 4096 + (size_t)B_SZ * 512;

    // 1) all prep in one dispatch (incl. nbias zero)
    prep_kernel<<<12416, 256, 0, stream>>>(
        obs, category, q_w0, q_b0, q_w1, q_w2, q_w3, v_w0, v_b0, v_w1, v_w2,
        obs_bf, w0t, w1t, w2t, w3t, vw0t, vw1t, vw2t, w0aug, vw0aug,
        acts_bf, out_nbias);

    // 2) P: p = obs@W0a (fp32) || pv = obs@vW0 (fp32), no bias
    gemm_dual<<<256, 256, 0, stream>>>(
        obs_bf, w0t, nullptr, p, 128, 0, 128,
        obs_bf, vw0t, nullptr, pv, 128, 0);

    // 3) fused q+v MLP (2048 q-blocks + 64 v-blocks), 512 threads
    fused_kernel<<<2112, 512, 0, stream>>>(
        p, pv, acts_bf, w0aug, vw0aug, w1t, q_b1, w2t, q_b2, w3t, q_b3, out_adv,
        vw1t, v_b1, vw2t, v_b2, v_w3, v_b3, out_value);
}